// Round 2
// baseline (2788.880 us; speedup 1.0000x reference)
//
#include <hip/hip_runtime.h>
#include <math.h>

// SegmentalLM forward, fp32 reference-faithful implementation.
// V=4000 E=H=256 M=128 B=32 L=4, S=126, SB=4032, NROW=5*4032=20160.
//
// R2: encoder recurrence restructured. Old version streamed 1MB WhhT from L2
// per step per block (32 blocks) and sat at the ~115 GB/s per-CU L2 ceiling
// (1113 us). New version: 256 blocks = 8 slices x 32 batches; each block owns
// 32 units (128 gate rows), weights preloaded into VGPRs (32 float4/thread),
// per-step cross-block handshake via release/acquire flags (device scope).

#define LOGNEG -1000000.0f
#define GF_BIAS 1
#define GF_TANH 2
#define GF_DECSTEP 4
#define GF_ACC 8

__device__ __forceinline__ float sigmf_(float x){ return 1.0f/(1.0f+expf(-x)); }

// ---------------- embed + is_single ----------------
__global__ __launch_bounds__(256) void k_embed(
    const int* __restrict__ x, const float* __restrict__ emb,
    float* __restrict__ emb_in, float* __restrict__ is_s)
{
    int ri = blockIdx.x;
    int m = ri >> 5, b = ri & 31;
    int tok = x[b*128 + m];
    int h = threadIdx.x;
    emb_in[(size_t)ri*256 + h] = emb[(size_t)tok*256 + h];
    if (h == 0) is_s[ri] = (tok <= 2) ? LOGNEG : 0.0f;
}

// ---------------- bias sums ----------------
__global__ __launch_bounds__(256) void k_prep(
    const float* __restrict__ ebih, const float* __restrict__ ebhh, float* __restrict__ bias_e,
    const float* __restrict__ dbih, const float* __restrict__ dbhh, float* __restrict__ bias_d)
{
    int j = blockIdx.x*256 + threadIdx.x;
    if (j < 1024){ bias_e[j] = ebih[j]+ebhh[j]; bias_d[j] = dbih[j]+dbhh[j]; }
}

// ---------------- generic tiled GEMM: C = A(M,K) @ W(N,K)^T (+bias)(+acc)(+decstep base)(tanh) ----------------
__global__ __launch_bounds__(256) void k_gemm(
    const float* __restrict__ A, const float* __restrict__ W,
    const float* __restrict__ bias, float* __restrict__ C,
    int K, int N, int flags,
    const float* __restrict__ XgI, const float* __restrict__ bsum, int jstep)
{
    __shared__ float As[16][68];
    __shared__ float Bs[16][68];
    int tid = threadIdx.x;
    int tx = tid & 15, ty = tid >> 4;
    int rowBlk = blockIdx.y * 64, colBlk = blockIdx.x * 64;
    int lr = tid >> 2;
    int lk = (tid & 3) * 4;
    const float* Aload = A + (size_t)(rowBlk + lr)*K + lk;
    const float* Wload = W + (size_t)(colBlk + lr)*K + lk;
    float acc[4][4] = {};
    for (int kt = 0; kt < K; kt += 16){
        float4 av = *(const float4*)(Aload + kt);
        float4 wv = *(const float4*)(Wload + kt);
        As[lk+0][lr] = av.x; As[lk+1][lr] = av.y; As[lk+2][lr] = av.z; As[lk+3][lr] = av.w;
        Bs[lk+0][lr] = wv.x; Bs[lk+1][lr] = wv.y; Bs[lk+2][lr] = wv.z; Bs[lk+3][lr] = wv.w;
        __syncthreads();
        #pragma unroll
        for (int k = 0; k < 16; k++){
            float4 a4 = *(const float4*)&As[k][ty*4];
            float4 b4 = *(const float4*)&Bs[k][tx*4];
            acc[0][0] += a4.x*b4.x; acc[0][1] += a4.x*b4.y; acc[0][2] += a4.x*b4.z; acc[0][3] += a4.x*b4.w;
            acc[1][0] += a4.y*b4.x; acc[1][1] += a4.y*b4.y; acc[1][2] += a4.y*b4.z; acc[1][3] += a4.y*b4.w;
            acc[2][0] += a4.z*b4.x; acc[2][1] += a4.z*b4.y; acc[2][2] += a4.z*b4.z; acc[2][3] += a4.z*b4.w;
            acc[3][0] += a4.w*b4.x; acc[3][1] += a4.w*b4.y; acc[3][2] += a4.w*b4.z; acc[3][3] += a4.w*b4.w;
        }
        __syncthreads();
    }
    #pragma unroll
    for (int i = 0; i < 4; i++){
        int r = rowBlk + ty*4 + i;
        #pragma unroll
        for (int j = 0; j < 4; j++){
            int c = colBlk + tx*4 + j;
            float v = acc[i][j];
            if (flags & GF_ACC)  v += C[(size_t)r*N + c];
            if (flags & GF_BIAS) v += bias[c];
            if (flags & GF_DECSTEP){
                int s = r >> 5, b = r & 31;
                int m = s + jstep;
                v += (m < 128) ? XgI[((size_t)(m*32+b))*1024 + c] : bsum[c];
            }
            if (flags & GF_TANH) v = tanhf(v);
            C[(size_t)r*N + c] = v;
        }
    }
}

// ---------------- encoder LSTM recurrence, R2 design ----------------
// Grid 256 blocks x 256 threads. b = bx % 32 (batch), j = bx / 32 (slice).
// Slice owns units U0=j*32 .. U0+31 (128 gate rows). Thread t: local row
// r = t & 127 (gate=r>>5, u=r&31), k-half = t >> 7. Weights (128 floats) held
// in 32 float4 VGPRs, loaded once from enc_Whh (row-major, contiguous).
// Per step: acquire 8 flags -> stage h (1KB) to LDS -> dot from VGPR weights
// (h reads are wave-broadcast) -> gate partials to LDS -> 32 threads do the
// LSTM pointwise, write h-slice (global, parity double-buffered) ->
// __syncthreads + __threadfence + release flag.
__global__ __launch_bounds__(256) void k_enc_rnn(
    const float* __restrict__ Xg, const float* __restrict__ Whh,
    const float* __restrict__ h0, const float* __restrict__ c0,
    float* __restrict__ enc_out, float* __restrict__ hbuf,
    unsigned int* __restrict__ flags)
{
    const int bx = blockIdx.x;
    const int b = bx & 31;          // batch  (8 slice-blocks of a batch are
    const int j = bx >> 5;          // slice   bx%8-congruent -> same XCD)
    const int U0 = j * 32;
    const int tid = threadIdx.x;
    const int r = tid & 127;        // local gate row
    const int khalf = tid >> 7;     // 0|1
    const int gate = r >> 5, u = r & 31;
    const int grow = gate * 256 + U0 + u;   // global gate row in [0,1024)

    __shared__ float h_s[256];
    __shared__ float g_s[128][2];

    // preload weights into VGPRs: Whh[grow][khalf*128 .. +128)
    float4 w[32];
    {
        const float4* wsrc = (const float4*)(Whh + (size_t)grow*256 + khalf*128);
        #pragma unroll
        for (int kk = 0; kk < 32; kk++) w[kk] = wsrc[kk];
    }
    // persistent cell state for this block's units (valid on threads < 32)
    float c = (tid < 32) ? c0[U0 + tid] : 0.0f;

    const unsigned fbase = b * 8;

    for (int t = 0; t < 128; t++){
        // issue Xg load early (independent of handshake)
        float xg = 0.0f;
        if (khalf == 0) xg = Xg[((size_t)(t*32+b))*1024 + grow];

        // wait for all 8 slices of this batch to have produced h_t
        if (tid < 8){
            const unsigned want = (unsigned)t;
            while (__hip_atomic_load(&flags[fbase + tid], __ATOMIC_ACQUIRE,
                                     __HIP_MEMORY_SCOPE_AGENT) < want)
                __builtin_amdgcn_s_sleep(2);
        }
        __syncthreads();

        // stage h_t into LDS
        if (tid < 64){
            const float* src = (t == 0) ? h0 : (hbuf + ((size_t)(t & 1))*32*256 + (size_t)b*256);
            ((float4*)h_s)[tid] = ((const float4*)src)[tid];
        }
        __syncthreads();

        // partial dot over this thread's k-half (h reads broadcast per wave)
        float acc = xg;
        const float4* h4 = (const float4*)h_s + khalf*32;
        #pragma unroll
        for (int kk = 0; kk < 32; kk++){
            float4 hv = h4[kk];
            acc += w[kk].x*hv.x + w[kk].y*hv.y + w[kk].z*hv.z + w[kk].w*hv.w;
        }
        g_s[r][khalf] = acc;
        __syncthreads();

        // pointwise LSTM update for owned units
        if (tid < 32){
            float gi = g_s[tid][0]      + g_s[tid][1];
            float gf = g_s[32+tid][0]   + g_s[32+tid][1];
            float gg = g_s[64+tid][0]   + g_s[64+tid][1];
            float go = g_s[96+tid][0]   + g_s[96+tid][1];
            c = sigmf_(gf)*c + sigmf_(gi)*tanhf(gg);
            float hn = sigmf_(go)*tanhf(c);
            enc_out[((size_t)(t*32+b))*256 + U0 + tid] = 0.5f*hn;
            hbuf[((size_t)((t+1) & 1))*32*256 + (size_t)b*256 + U0 + tid] = hn;
        }
        __syncthreads();
        if (tid == 0){
            __threadfence();
            __hip_atomic_store(&flags[fbase + j], (unsigned)(t+1), __ATOMIC_RELEASE,
                               __HIP_MEMORY_SCOPE_AGENT);
        }
    }
}

// ---------------- decoder LSTM pointwise update ----------------
__global__ __launch_bounds__(256) void k_pointwise(
    const float* __restrict__ gbuf, float* __restrict__ h, float* __restrict__ c,
    float* __restrict__ dec_out_j)
{
    int sb = blockIdx.x, u = threadIdx.x;
    const float* g = gbuf + (size_t)sb*1024;
    float gi = g[u], gf = g[256+u], gg = g[512+u], go = g[768+u];
    float cv = c[(size_t)sb*256+u];
    cv = sigmf_(gf)*cv + sigmf_(gi)*tanhf(gg);
    float hv = sigmf_(go)*tanhf(cv);
    c[(size_t)sb*256+u] = cv;
    h[(size_t)sb*256+u] = hv;
    dec_out_j[(size_t)sb*256+u] = hv;
}

// ---------------- logits + fused online logsumexp + tgt/EOS extraction ----------------
__global__ __launch_bounds__(256) void k_logits(
    const float* __restrict__ Arows, const float* __restrict__ emb,
    const float* __restrict__ e2v_b, const int* __restrict__ x,
    float* __restrict__ pm, float* __restrict__ ps,
    float* __restrict__ pzt, float* __restrict__ pze)
{
    const int NROW = 20160;
    __shared__ float As[32][68];
    __shared__ float Bs[32][132];
    __shared__ int   tgt_s[64];
    __shared__ float eb_s[128];
    int tid = threadIdx.x;
    int rb = blockIdx.x, hf = blockIdx.y;
    int r0 = rb * 64;
    if (tid < 64){
        int r = r0 + tid;
        int t = r / 4032, sb = r % 4032;
        int s = sb >> 5, b = sb & 31;
        int m = s + 1 + t;
        tgt_s[tid] = (m < 128) ? x[b*128 + m] : 0;
    }
    int tx = tid & 15, ty = tid >> 4;
    float rm[4], rs[4], rzt[4], rze[4];
    #pragma unroll
    for (int i = 0; i < 4; i++){ rm[i] = -1e30f; rs[i] = 0.f; rzt[i] = -1e30f; rze[i] = -1e30f; }
    int lrA = tid >> 2, lkA = (tid & 3) * 8;
    int lrB = tid >> 1, lkB = (tid & 1) * 16;
    const float* Abase = Arows + (size_t)(r0 + lrA)*256 + lkA;
    for (int vt = 0; vt < 16; vt++){
        __syncthreads();
        int v0 = hf*2048 + vt*128;
        if (tid < 128){
            int v = v0 + tid;
            eb_s[tid] = (v < 4000) ? e2v_b[v] : 0.0f;
        }
        int vb = v0 + lrB;
        const float* Bbase = emb + (size_t)((vb < 4000) ? vb : 0)*256 + lkB;
        float acc[4][8] = {};
        for (int kc = 0; kc < 256; kc += 32){
            float4 a0 = *(const float4*)(Abase + kc);
            float4 a1 = *(const float4*)(Abase + kc + 4);
            As[lkA+0][lrA]=a0.x; As[lkA+1][lrA]=a0.y; As[lkA+2][lrA]=a0.z; As[lkA+3][lrA]=a0.w;
            As[lkA+4][lrA]=a1.x; As[lkA+5][lrA]=a1.y; As[lkA+6][lrA]=a1.z; As[lkA+7][lrA]=a1.w;
            const float* Bp = Bbase + kc;
            float4 b0v = *(const float4*)(Bp);
            float4 b1v = *(const float4*)(Bp+4);
            float4 b2v = *(const float4*)(Bp+8);
            float4 b3v = *(const float4*)(Bp+12);
            Bs[lkB+ 0][lrB]=b0v.x; Bs[lkB+ 1][lrB]=b0v.y; Bs[lkB+ 2][lrB]=b0v.z; Bs[lkB+ 3][lrB]=b0v.w;
            Bs[lkB+ 4][lrB]=b1v.x; Bs[lkB+ 5][lrB]=b1v.y; Bs[lkB+ 6][lrB]=b1v.z; Bs[lkB+ 7][lrB]=b1v.w;
            Bs[lkB+ 8][lrB]=b2v.x; Bs[lkB+ 9][lrB]=b2v.y; Bs[lkB+10][lrB]=b2v.z; Bs[lkB+11][lrB]=b2v.w;
            Bs[lkB+12][lrB]=b3v.x; Bs[lkB+13][lrB]=b3v.y; Bs[lkB+14][lrB]=b3v.z; Bs[lkB+15][lrB]=b3v.w;
            __syncthreads();
            #pragma unroll
            for (int k = 0; k < 32; k++){
                float4 a4 = *(const float4*)&As[k][ty*4];
                float4 p0 = *(const float4*)&Bs[k][tx*8];
                float4 p1 = *(const float4*)&Bs[k][tx*8+4];
                float av[4] = {a4.x,a4.y,a4.z,a4.w};
                float bv[8] = {p0.x,p0.y,p0.z,p0.w,p1.x,p1.y,p1.z,p1.w};
                #pragma unroll
                for (int i = 0; i < 4; i++){
                    #pragma unroll
                    for (int j = 0; j < 8; j++) acc[i][j] += av[i]*bv[j];
                }
            }
            __syncthreads();
        }
        #pragma unroll
        for (int i = 0; i < 4; i++){
            float z[8];
            float tm = -1e30f;
            #pragma unroll
            for (int j = 0; j < 8; j++){
                int v = v0 + tx*8 + j;
                z[j] = acc[i][j] + eb_s[tx*8+j];
                if (v < 4000) tm = fmaxf(tm, z[j]);
            }
            if (tm > -1e29f){
                float mn = fmaxf(rm[i], tm);
                float ssum = rs[i]*expf(rm[i]-mn);
                #pragma unroll
                for (int j = 0; j < 8; j++){
                    int v = v0 + tx*8 + j;
                    if (v < 4000) ssum += expf(z[j]-mn);
                }
                rm[i] = mn; rs[i] = ssum;
            }
            int tg = tgt_s[ty*4+i];
            #pragma unroll
            for (int j = 0; j < 8; j++){
                int v = v0 + tx*8 + j;
                if (v == tg) rzt[i] = z[j];
                if (v == 3)  rze[i] = z[j];
            }
        }
    }
    #pragma unroll
    for (int i = 0; i < 4; i++){
        for (int off = 1; off < 16; off <<= 1){
            float om = __shfl_xor(rm[i], off, 64);
            float os = __shfl_xor(rs[i], off, 64);
            float mn = fmaxf(rm[i], om);
            rs[i] = rs[i]*expf(rm[i]-mn) + os*expf(om-mn);
            rm[i] = mn;
            rzt[i] = fmaxf(rzt[i], __shfl_xor(rzt[i], off, 64));
            rze[i] = fmaxf(rze[i], __shfl_xor(rze[i], off, 64));
        }
    }
    if (tx == 0){
        #pragma unroll
        for (int i = 0; i < 4; i++){
            int r = r0 + ty*4 + i;
            pm [hf*NROW + r] = rm[i];
            ps [hf*NROW + r] = rs[i];
            pzt[hf*NROW + r] = rzt[i];
            pze[hf*NROW + r] = rze[i];
        }
    }
}

// ---------------- combine v-halves -> tlp / eos ----------------
__global__ __launch_bounds__(256) void k_combine(
    const float* __restrict__ pm, const float* __restrict__ ps,
    const float* __restrict__ pzt, const float* __restrict__ pze,
    float* __restrict__ tlp, float* __restrict__ eosb)
{
    int r = blockIdx.x*256 + threadIdx.x;
    if (r >= 20160) return;
    float m0 = pm[r], m1 = pm[20160+r];
    float s0 = ps[r], s1 = ps[20160+r];
    float M = fmaxf(m0, m1);
    float lse = M + logf(s0*expf(m0-M) + s1*expf(m1-M));
    float zt = fmaxf(pzt[r], pzt[20160+r]);
    float ze = fmaxf(pze[r], pze[20160+r]);
    int t = r / 4032, sb = r % 4032;
    int s = sb >> 5, b = sb & 31;
    if (t < 4)  tlp[(t*126+s)*32 + b]      = zt - lse;
    if (t >= 1) eosb[((t-1)*126+s)*32 + b] = ze - lse;
}

// ---------------- segmental DP + final reduction ----------------
__global__ __launch_bounds__(128) void k_finalize(
    const float* __restrict__ tlp, const float* __restrict__ eosb,
    const float* __restrict__ is_s, const int* __restrict__ lengths,
    float* __restrict__ seg_g, float* __restrict__ out)
{
    int tid = threadIdx.x;
    int k = tid >> 5, b = tid & 31;
    for (int s = 0; s < 126; s++){
        float cum = 0.f;
        for (int kk = 0; kk <= k; kk++) cum += tlp[(kk*126+s)*32 + b];
        if (k >= 1){
            for (int kk = 1; kk <= k; kk++){
                int m = s+1+kk;
                if (m < 128) cum += is_s[m*32+b];
            }
            cum += is_s[(s+1)*32 + b];
        }
        float lp = cum + eosb[(k*126+s)*32 + b];
        int jl = min(4, 126 - s);
        if (k >= jl) lp = LOGNEG;
        seg_g[(s*4+k)*32 + b] = lp;
    }
    __threadfence_block();
    __syncthreads();
    __shared__ float nll_s[32];
    if (tid < 32){
        int target = lengths[tid] - 2;
        float b0 = 0.f, b1 = LOGNEG, b2 = LOGNEG, b3 = LOGNEG;
        float nllb = 0.f;
        for (int e = 1; e <= 126; e++){
            float v0 = b0 + seg_g[((e-1)*4+0)*32 + tid];
            float v1 = b1 + ((e >= 2) ? seg_g[((e-2)*4+1)*32 + tid] : LOGNEG);
            float v2 = b2 + ((e >= 3) ? seg_g[((e-3)*4+2)*32 + tid] : LOGNEG);
            float v3 = b3 + ((e >= 4) ? seg_g[((e-4)*4+3)*32 + tid] : LOGNEG);
            float mx = fmaxf(fmaxf(v0,v1), fmaxf(v2,v3));
            float a = mx + logf(expf(v0-mx)+expf(v1-mx)+expf(v2-mx)+expf(v3-mx));
            if (e == target) nllb = -a;
            b3 = b2; b2 = b1; b1 = b0; b0 = a;
        }
        nll_s[tid] = nllb;
    }
    __syncthreads();
    if (tid == 0){
        float tot = 0.f; int lsum = 0;
        for (int i = 0; i < 32; i++){ tot += nll_s[i]; lsum += lengths[i]; }
        out[0] = tot / (float)(lsum - 64);
    }
}

extern "C" void kernel_launch(void* const* d_in, const int* in_sizes, int n_in,
                              void* d_out, int out_size, void* d_ws, size_t ws_size,
                              hipStream_t stream)
{
    const int*   x        = (const int*)  d_in[0];
    const int*   lengths  = (const int*)  d_in[1];
    const float* emb      = (const float*)d_in[2];
    const float* e2v_b    = (const float*)d_in[3];
    const float* enc_Wih  = (const float*)d_in[4];
    const float* enc_Whh  = (const float*)d_in[5];
    const float* enc_bih  = (const float*)d_in[6];
    const float* enc_bhh  = (const float*)d_in[7];
    const float* enc_h0   = (const float*)d_in[8];
    const float* enc_c0   = (const float*)d_in[9];
    const float* dec_Wih  = (const float*)d_in[10];
    const float* dec_Whh  = (const float*)d_in[11];
    const float* dec_bih  = (const float*)d_in[12];
    const float* dec_bhh  = (const float*)d_in[13];
    const float* dht_W    = (const float*)d_in[14];
    const float* dht_b    = (const float*)d_in[15];
    const float* sos_W    = (const float*)d_in[16];
    const float* sos_b    = (const float*)d_in[17];
    float* out = (float*)d_out;

    char* wsb = (char*)d_ws;
    size_t off = 0;
    auto alloc = [&](size_t elems)->float*{
        float* p = (float*)(wsb + off);
        off += ((elems*sizeof(float) + 255)/256)*256;
        return p;
    };
    float* emb_in  = alloc((size_t)4096*256);
    float* is_s    = alloc(4096);
    float* Xg_enc  = alloc((size_t)4096*1024);   // reused as XgI after encoder
    float* enc_out = alloc((size_t)4096*256);
    float* sos     = alloc((size_t)4032*256);
    float* dec_h   = alloc((size_t)4032*256);
    float* dec_c   = alloc((size_t)4032*256);
    float* gbuf    = alloc((size_t)4032*1024);
    float* dec_out = alloc((size_t)5*4032*256);
    float* bias_e  = alloc(1024);
    float* bias_d  = alloc(1024);
    float* pm      = alloc((size_t)2*20160);
    float* ps      = alloc((size_t)2*20160);
    float* pzt     = alloc((size_t)2*20160);
    float* pze     = alloc((size_t)2*20160);
    float* tlp     = alloc((size_t)4*126*32);
    float* eosb    = alloc((size_t)4*126*32);
    float* seg_g   = alloc((size_t)126*4*32);
    float* hbuf    = alloc((size_t)2*32*256);
    unsigned int* flags = (unsigned int*)alloc(256);
    (void)ws_size; (void)in_sizes; (void)n_in; (void)out_size;

    // 0. zero handshake flags + dec_c (d_ws is poisoned 0xAA every call)
    hipMemsetAsync(flags, 0, 256*sizeof(unsigned int), stream);
    hipMemsetAsync(dec_c, 0, (size_t)4032*256*sizeof(float), stream);
    // 1. bias sums
    k_prep<<<4, 256, 0, stream>>>(enc_bih, enc_bhh, bias_e, dec_bih, dec_bhh, bias_d);
    // 2. embeddings + is_single
    k_embed<<<4096, 256, 0, stream>>>(x, emb, emb_in, is_s);
    // 3. encoder input-side gates: Xg_enc = emb_in @ enc_Wih^T + (bih+bhh)
    k_gemm<<<dim3(16,64), 256, 0, stream>>>(emb_in, enc_Wih, bias_e, Xg_enc, 256, 1024, GF_BIAS, nullptr, nullptr, 0);
    // 4. encoder recurrence (256 blocks, VGPR-resident weights, flag handshake)
    k_enc_rnn<<<256, 256, 0, stream>>>(Xg_enc, enc_Whh, enc_h0, enc_c0, enc_out, hbuf, flags);
    // 5. sos = enc_prev @ sos_W^T + sos_b
    k_gemm<<<dim3(4,63), 256, 0, stream>>>(enc_out, sos_W, sos_b, sos, 256, 256, GF_BIAS, nullptr, nullptr, 0);
    // 6. dec_h0 = tanh(enc_prev @ dht_W^T + dht_b)
    k_gemm<<<dim3(4,63), 256, 0, stream>>>(enc_out, dht_W, dht_b, dec_h, 256, 256, GF_BIAS|GF_TANH, nullptr, nullptr, 0);
    // 8. input gates for decoder step 0: gbuf = sos @ dec_Wih^T + (bih+bhh)
    k_gemm<<<dim3(16,63), 256, 0, stream>>>(sos, dec_Wih, bias_d, gbuf, 256, 1024, GF_BIAS, nullptr, nullptr, 0);
    // 9. input gates for steps >=1: XgI = emb_in @ dec_Wih^T + bias (reuses Xg_enc)
    k_gemm<<<dim3(16,64), 256, 0, stream>>>(emb_in, dec_Wih, bias_d, Xg_enc, 256, 1024, GF_BIAS, nullptr, nullptr, 0);
    // 10. decoder recurrence (5 steps)
    for (int j = 0; j < 5; j++){
        if (j == 0){
            k_gemm<<<dim3(16,63), 256, 0, stream>>>(dec_h, dec_Whh, nullptr, gbuf, 256, 1024, GF_ACC, nullptr, nullptr, 0);
        } else {
            k_gemm<<<dim3(16,63), 256, 0, stream>>>(dec_h, dec_Whh, nullptr, gbuf, 256, 1024, GF_DECSTEP, Xg_enc, bias_d, j);
        }
        k_pointwise<<<4032, 256, 0, stream>>>(gbuf, dec_h, dec_c, dec_out + (size_t)j*4032*256);
    }
    // 11. fused logits + logsumexp + tgt/EOS extraction
    k_logits<<<dim3(315,2), 256, 0, stream>>>(dec_out, emb, e2v_b, x, pm, ps, pzt, pze);
    // 12. combine halves
    k_combine<<<79, 256, 0, stream>>>(pm, ps, pzt, pze, tlp, eosb);
    // 13. segmental DP + reduction
    k_finalize<<<1, 128, 0, stream>>>(tlp, eosb, is_s, lengths, seg_g, out);
}

// Round 3
// 1666.827 us; speedup vs baseline: 1.6732x; 1.6732x over previous
//
#include <hip/hip_runtime.h>
#include <math.h>

// SegmentalLM forward, fp32 implementation (encoder Whh in f16).
// V=4000 E=H=256 M=128 B=32 L=4, S=126, SB=4032, NROW=5*4032=20160.
//
// R3 encoder: one block per batch (NO cross-block sync — R2 showed a
// device-scope handshake costs ~10us/step across XCDs). Whh packed f16:
// 14 pair-groups in VGPRs + 9 in LDS + 9 streamed from L2 per step
// (144KB/step vs R1's 1MB/step on the ~115GB/s per-CU L2 path).
// Dot via v_dot2_f32_f16 (2 MACs/inst, no unpack).

#define LOGNEG -1000000.0f
#define GF_BIAS 1
#define GF_TANH 2
#define GF_DECSTEP 4
#define GF_ACC 8

typedef unsigned int uint32;
typedef _Float16 half2_t __attribute__((ext_vector_type(2)));

__device__ __forceinline__ float sigmf_(float x){ return 1.0f/(1.0f+expf(-x)); }

__device__ __forceinline__ float dot2f(uint32 w, uint32 h, float acc){
#if __has_builtin(__builtin_amdgcn_fdot2)
    return __builtin_amdgcn_fdot2(__builtin_bit_cast(half2_t, w),
                                  __builtin_bit_cast(half2_t, h), acc, false);
#else
    half2_t a = __builtin_bit_cast(half2_t, w);
    half2_t b = __builtin_bit_cast(half2_t, h);
    return acc + (float)a[0]*(float)b[0] + (float)a[1]*(float)b[1];
#endif
}

// ---------------- embed + is_single ----------------
__global__ __launch_bounds__(256) void k_embed(
    const int* __restrict__ x, const float* __restrict__ emb,
    float* __restrict__ emb_in, float* __restrict__ is_s)
{
    int ri = blockIdx.x;
    int m = ri >> 5, b = ri & 31;
    int tok = x[b*128 + m];
    int h = threadIdx.x;
    emb_in[(size_t)ri*256 + h] = emb[(size_t)tok*256 + h];
    if (h == 0) is_s[ri] = (tok <= 2) ? LOGNEG : 0.0f;
}

// ---------------- bias sums ----------------
__global__ __launch_bounds__(256) void k_prep(
    const float* __restrict__ ebih, const float* __restrict__ ebhh, float* __restrict__ bias_e,
    const float* __restrict__ dbih, const float* __restrict__ dbhh, float* __restrict__ bias_d)
{
    int j = blockIdx.x*256 + threadIdx.x;
    if (j < 1024){ bias_e[j] = ebih[j]+ebhh[j]; bias_d[j] = dbih[j]+dbhh[j]; }
}

// ---------------- pack enc_Whh (1024x256 f32) -> f16 pair-groups ----------------
// Layout: Wpk[pg][row][d] (pg<32, row<1024, d<4), dword d = f16 pair
// (W[row][pg*8+2d], W[row][pg*8+2d+1]).  Linear idx = pg*4096 + row*4 + d.
__global__ __launch_bounds__(256) void k_prep_w(
    const float* __restrict__ W, uint32* __restrict__ Wpk)
{
    int idx = blockIdx.x*256 + threadIdx.x;   // < 131072
    int pg = idx >> 12, rem = idx & 4095;
    int row = rem >> 2, d = rem & 3;
    int k = pg*8 + d*2;
    union { _Float16 h[2]; uint32 u; } cv;
    cv.h[0] = (_Float16)W[row*256 + k];
    cv.h[1] = (_Float16)W[row*256 + k + 1];
    Wpk[idx] = cv.u;
}

// ---------------- generic tiled GEMM: C = A(M,K) @ W(N,K)^T ----------------
__global__ __launch_bounds__(256) void k_gemm(
    const float* __restrict__ A, const float* __restrict__ W,
    const float* __restrict__ bias, float* __restrict__ C,
    int K, int N, int flags,
    const float* __restrict__ XgI, const float* __restrict__ bsum, int jstep)
{
    __shared__ float As[16][68];
    __shared__ float Bs[16][68];
    int tid = threadIdx.x;
    int tx = tid & 15, ty = tid >> 4;
    int rowBlk = blockIdx.y * 64, colBlk = blockIdx.x * 64;
    int lr = tid >> 2;
    int lk = (tid & 3) * 4;
    const float* Aload = A + (size_t)(rowBlk + lr)*K + lk;
    const float* Wload = W + (size_t)(colBlk + lr)*K + lk;
    float acc[4][4] = {};
    for (int kt = 0; kt < K; kt += 16){
        float4 av = *(const float4*)(Aload + kt);
        float4 wv = *(const float4*)(Wload + kt);
        As[lk+0][lr] = av.x; As[lk+1][lr] = av.y; As[lk+2][lr] = av.z; As[lk+3][lr] = av.w;
        Bs[lk+0][lr] = wv.x; Bs[lk+1][lr] = wv.y; Bs[lk+2][lr] = wv.z; Bs[lk+3][lr] = wv.w;
        __syncthreads();
        #pragma unroll
        for (int k = 0; k < 16; k++){
            float4 a4 = *(const float4*)&As[k][ty*4];
            float4 b4 = *(const float4*)&Bs[k][tx*4];
            acc[0][0] += a4.x*b4.x; acc[0][1] += a4.x*b4.y; acc[0][2] += a4.x*b4.z; acc[0][3] += a4.x*b4.w;
            acc[1][0] += a4.y*b4.x; acc[1][1] += a4.y*b4.y; acc[1][2] += a4.y*b4.z; acc[1][3] += a4.y*b4.w;
            acc[2][0] += a4.z*b4.x; acc[2][1] += a4.z*b4.y; acc[2][2] += a4.z*b4.z; acc[2][3] += a4.z*b4.w;
            acc[3][0] += a4.w*b4.x; acc[3][1] += a4.w*b4.y; acc[3][2] += a4.w*b4.z; acc[3][3] += a4.w*b4.w;
        }
        __syncthreads();
    }
    #pragma unroll
    for (int i = 0; i < 4; i++){
        int r = rowBlk + ty*4 + i;
        #pragma unroll
        for (int j = 0; j < 4; j++){
            int c = colBlk + tx*4 + j;
            float v = acc[i][j];
            if (flags & GF_ACC)  v += C[(size_t)r*N + c];
            if (flags & GF_BIAS) v += bias[c];
            if (flags & GF_DECSTEP){
                int s = r >> 5, b = r & 31;
                int m = s + jstep;
                v += (m < 128) ? XgI[((size_t)(m*32+b))*1024 + c] : bsum[c];
            }
            if (flags & GF_TANH) v = tanhf(v);
            C[(size_t)r*N + c] = v;
        }
    }
}

// ---------------- encoder LSTM recurrence, R3 ----------------
// 32 blocks x 1024 threads. Block = batch b, thread = gate row.
// Dynamic LDS: 9 pg of weights (147456B) + h f16 (512B) + g (4096B) = 152064B.
__global__ __launch_bounds__(1024) void k_enc_rnn(
    const float* __restrict__ Xg, const uint32* __restrict__ Wpk,
    const float* __restrict__ h0, const float* __restrict__ c0,
    float* __restrict__ enc_out)
{
    extern __shared__ char smem[];
    uint32* wlds = (uint32*)smem;                 // [9][1024][4]
    uint32* h_u  = (uint32*)(smem + 147456);      // 128 dwords = 256 f16
    float*  g_s  = (float*)(smem + 147968);       // 1024
    const int b = blockIdx.x, tid = threadIdx.x;
    const uint4* pk4 = (const uint4*)Wpk;         // [32][1024]

    // resident weights: pg 0..13 in VGPRs, pg 14..22 in LDS, pg 23..31 streamed
    uint4 wreg[14];
    #pragma unroll
    for (int pg = 0; pg < 14; pg++) wreg[pg] = pk4[pg*1024 + tid];
    #pragma unroll
    for (int i = 0; i < 9; i++) ((uint4*)wlds)[i*1024 + tid] = pk4[(14+i)*1024 + tid];

    float c = 0.f;
    if (tid < 256){
        c = c0[tid];
        ((_Float16*)h_u)[tid] = (_Float16)h0[tid];
    }
    __syncthreads();
    const uint4* hu4 = (const uint4*)h_u;         // 32 pair-group chunks
    const uint4* wl4 = (const uint4*)wlds;

    for (int t = 0; t < 128; t++){
        float xg = Xg[((size_t)(t*32+b))*1024 + tid];
        uint4 sv[9];
        #pragma unroll
        for (int i = 0; i < 9; i++) sv[i] = pk4[(23+i)*1024 + tid];

        float acc = xg;
        #pragma unroll
        for (int pg = 0; pg < 14; pg++){
            uint4 hh = hu4[pg];
            acc = dot2f(wreg[pg].x, hh.x, acc);
            acc = dot2f(wreg[pg].y, hh.y, acc);
            acc = dot2f(wreg[pg].z, hh.z, acc);
            acc = dot2f(wreg[pg].w, hh.w, acc);
        }
        #pragma unroll
        for (int i = 0; i < 9; i++){
            uint4 wv = wl4[i*1024 + tid];
            uint4 hh = hu4[14+i];
            acc = dot2f(wv.x, hh.x, acc);
            acc = dot2f(wv.y, hh.y, acc);
            acc = dot2f(wv.z, hh.z, acc);
            acc = dot2f(wv.w, hh.w, acc);
        }
        #pragma unroll
        for (int i = 0; i < 9; i++){
            uint4 hh = hu4[23+i];
            acc = dot2f(sv[i].x, hh.x, acc);
            acc = dot2f(sv[i].y, hh.y, acc);
            acc = dot2f(sv[i].z, hh.z, acc);
            acc = dot2f(sv[i].w, hh.w, acc);
        }
        g_s[tid] = acc;
        __syncthreads();
        if (tid < 256){
            float gi = g_s[tid], gf = g_s[256+tid], gg = g_s[512+tid], go = g_s[768+tid];
            c = sigmf_(gf)*c + sigmf_(gi)*tanhf(gg);
            float hn = sigmf_(go)*tanhf(c);
            enc_out[((size_t)(t*32+b))*256 + tid] = 0.5f*hn;
            ((_Float16*)h_u)[tid] = (_Float16)hn;
        }
        __syncthreads();
    }
}

// ---------------- decoder LSTM pointwise update ----------------
__global__ __launch_bounds__(256) void k_pointwise(
    const float* __restrict__ gbuf, float* __restrict__ h, float* __restrict__ c,
    float* __restrict__ dec_out_j)
{
    int sb = blockIdx.x, u = threadIdx.x;
    const float* g = gbuf + (size_t)sb*1024;
    float gi = g[u], gf = g[256+u], gg = g[512+u], go = g[768+u];
    float cv = c[(size_t)sb*256+u];
    cv = sigmf_(gf)*cv + sigmf_(gi)*tanhf(gg);
    float hv = sigmf_(go)*tanhf(cv);
    c[(size_t)sb*256+u] = cv;
    h[(size_t)sb*256+u] = hv;
    dec_out_j[(size_t)sb*256+u] = hv;
}

// ---------------- logits + fused online logsumexp + tgt/EOS extraction ----------------
__global__ __launch_bounds__(256) void k_logits(
    const float* __restrict__ Arows, const float* __restrict__ emb,
    const float* __restrict__ e2v_b, const int* __restrict__ x,
    float* __restrict__ pm, float* __restrict__ ps,
    float* __restrict__ pzt, float* __restrict__ pze)
{
    const int NROW = 20160;
    __shared__ float As[32][68];
    __shared__ float Bs[32][132];
    __shared__ int   tgt_s[64];
    __shared__ float eb_s[128];
    int tid = threadIdx.x;
    int rb = blockIdx.x, hf = blockIdx.y;
    int r0 = rb * 64;
    if (tid < 64){
        int r = r0 + tid;
        int t = r / 4032, sb = r % 4032;
        int s = sb >> 5, b = sb & 31;
        int m = s + 1 + t;
        tgt_s[tid] = (m < 128) ? x[b*128 + m] : 0;
    }
    int tx = tid & 15, ty = tid >> 4;
    float rm[4], rs[4], rzt[4], rze[4];
    #pragma unroll
    for (int i = 0; i < 4; i++){ rm[i] = -1e30f; rs[i] = 0.f; rzt[i] = -1e30f; rze[i] = -1e30f; }
    int lrA = tid >> 2, lkA = (tid & 3) * 8;
    int lrB = tid >> 1, lkB = (tid & 1) * 16;
    const float* Abase = Arows + (size_t)(r0 + lrA)*256 + lkA;
    for (int vt = 0; vt < 16; vt++){
        __syncthreads();
        int v0 = hf*2048 + vt*128;
        if (tid < 128){
            int v = v0 + tid;
            eb_s[tid] = (v < 4000) ? e2v_b[v] : 0.0f;
        }
        int vb = v0 + lrB;
        const float* Bbase = emb + (size_t)((vb < 4000) ? vb : 0)*256 + lkB;
        float acc[4][8] = {};
        for (int kc = 0; kc < 256; kc += 32){
            float4 a0 = *(const float4*)(Abase + kc);
            float4 a1 = *(const float4*)(Abase + kc + 4);
            As[lkA+0][lrA]=a0.x; As[lkA+1][lrA]=a0.y; As[lkA+2][lrA]=a0.z; As[lkA+3][lrA]=a0.w;
            As[lkA+4][lrA]=a1.x; As[lkA+5][lrA]=a1.y; As[lkA+6][lrA]=a1.z; As[lkA+7][lrA]=a1.w;
            const float* Bp = Bbase + kc;
            float4 b0v = *(const float4*)(Bp);
            float4 b1v = *(const float4*)(Bp+4);
            float4 b2v = *(const float4*)(Bp+8);
            float4 b3v = *(const float4*)(Bp+12);
            Bs[lkB+ 0][lrB]=b0v.x; Bs[lkB+ 1][lrB]=b0v.y; Bs[lkB+ 2][lrB]=b0v.z; Bs[lkB+ 3][lrB]=b0v.w;
            Bs[lkB+ 4][lrB]=b1v.x; Bs[lkB+ 5][lrB]=b1v.y; Bs[lkB+ 6][lrB]=b1v.z; Bs[lkB+ 7][lrB]=b1v.w;
            Bs[lkB+ 8][lrB]=b2v.x; Bs[lkB+ 9][lrB]=b2v.y; Bs[lkB+10][lrB]=b2v.z; Bs[lkB+11][lrB]=b2v.w;
            Bs[lkB+12][lrB]=b3v.x; Bs[lkB+13][lrB]=b3v.y; Bs[lkB+14][lrB]=b3v.z; Bs[lkB+15][lrB]=b3v.w;
            __syncthreads();
            #pragma unroll
            for (int k = 0; k < 32; k++){
                float4 a4 = *(const float4*)&As[k][ty*4];
                float4 p0 = *(const float4*)&Bs[k][tx*8];
                float4 p1 = *(const float4*)&Bs[k][tx*8+4];
                float av[4] = {a4.x,a4.y,a4.z,a4.w};
                float bv[8] = {p0.x,p0.y,p0.z,p0.w,p1.x,p1.y,p1.z,p1.w};
                #pragma unroll
                for (int i = 0; i < 4; i++){
                    #pragma unroll
                    for (int j = 0; j < 8; j++) acc[i][j] += av[i]*bv[j];
                }
            }
            __syncthreads();
        }
        #pragma unroll
        for (int i = 0; i < 4; i++){
            float z[8];
            float tm = -1e30f;
            #pragma unroll
            for (int j = 0; j < 8; j++){
                int v = v0 + tx*8 + j;
                z[j] = acc[i][j] + eb_s[tx*8+j];
                if (v < 4000) tm = fmaxf(tm, z[j]);
            }
            if (tm > -1e29f){
                float mn = fmaxf(rm[i], tm);
                float ssum = rs[i]*expf(rm[i]-mn);
                #pragma unroll
                for (int j = 0; j < 8; j++){
                    int v = v0 + tx*8 + j;
                    if (v < 4000) ssum += expf(z[j]-mn);
                }
                rm[i] = mn; rs[i] = ssum;
            }
            int tg = tgt_s[ty*4+i];
            #pragma unroll
            for (int j = 0; j < 8; j++){
                int v = v0 + tx*8 + j;
                if (v == tg) rzt[i] = z[j];
                if (v == 3)  rze[i] = z[j];
            }
        }
    }
    #pragma unroll
    for (int i = 0; i < 4; i++){
        for (int off = 1; off < 16; off <<= 1){
            float om = __shfl_xor(rm[i], off, 64);
            float os = __shfl_xor(rs[i], off, 64);
            float mn = fmaxf(rm[i], om);
            rs[i] = rs[i]*expf(rm[i]-mn) + os*expf(om-mn);
            rm[i] = mn;
            rzt[i] = fmaxf(rzt[i], __shfl_xor(rzt[i], off, 64));
            rze[i] = fmaxf(rze[i], __shfl_xor(rze[i], off, 64));
        }
    }
    if (tx == 0){
        #pragma unroll
        for (int i = 0; i < 4; i++){
            int r = r0 + ty*4 + i;
            pm [hf*NROW + r] = rm[i];
            ps [hf*NROW + r] = rs[i];
            pzt[hf*NROW + r] = rzt[i];
            pze[hf*NROW + r] = rze[i];
        }
    }
}

// ---------------- combine v-halves -> tlp / eos ----------------
__global__ __launch_bounds__(256) void k_combine(
    const float* __restrict__ pm, const float* __restrict__ ps,
    const float* __restrict__ pzt, const float* __restrict__ pze,
    float* __restrict__ tlp, float* __restrict__ eosb)
{
    int r = blockIdx.x*256 + threadIdx.x;
    if (r >= 20160) return;
    float m0 = pm[r], m1 = pm[20160+r];
    float s0 = ps[r], s1 = ps[20160+r];
    float M = fmaxf(m0, m1);
    float lse = M + logf(s0*expf(m0-M) + s1*expf(m1-M));
    float zt = fmaxf(pzt[r], pzt[20160+r]);
    float ze = fmaxf(pze[r], pze[20160+r]);
    int t = r / 4032, sb = r % 4032;
    int s = sb >> 5, b = sb & 31;
    if (t < 4)  tlp[(t*126+s)*32 + b]      = zt - lse;
    if (t >= 1) eosb[((t-1)*126+s)*32 + b] = ze - lse;
}

// ---------------- segmental DP + final reduction ----------------
__global__ __launch_bounds__(128) void k_finalize(
    const float* __restrict__ tlp, const float* __restrict__ eosb,
    const float* __restrict__ is_s, const int* __restrict__ lengths,
    float* __restrict__ seg_g, float* __restrict__ out)
{
    int tid = threadIdx.x;
    int k = tid >> 5, b = tid & 31;
    for (int s = 0; s < 126; s++){
        float cum = 0.f;
        for (int kk = 0; kk <= k; kk++) cum += tlp[(kk*126+s)*32 + b];
        if (k >= 1){
            for (int kk = 1; kk <= k; kk++){
                int m = s+1+kk;
                if (m < 128) cum += is_s[m*32+b];
            }
            cum += is_s[(s+1)*32 + b];
        }
        float lp = cum + eosb[(k*126+s)*32 + b];
        int jl = min(4, 126 - s);
        if (k >= jl) lp = LOGNEG;
        seg_g[(s*4+k)*32 + b] = lp;
    }
    __threadfence_block();
    __syncthreads();
    __shared__ float nll_s[32];
    if (tid < 32){
        int target = lengths[tid] - 2;
        float b0 = 0.f, b1 = LOGNEG, b2 = LOGNEG, b3 = LOGNEG;
        float nllb = 0.f;
        for (int e = 1; e <= 126; e++){
            float v0 = b0 + seg_g[((e-1)*4+0)*32 + tid];
            float v1 = b1 + ((e >= 2) ? seg_g[((e-2)*4+1)*32 + tid] : LOGNEG);
            float v2 = b2 + ((e >= 3) ? seg_g[((e-3)*4+2)*32 + tid] : LOGNEG);
            float v3 = b3 + ((e >= 4) ? seg_g[((e-4)*4+3)*32 + tid] : LOGNEG);
            float mx = fmaxf(fmaxf(v0,v1), fmaxf(v2,v3));
            float a = mx + logf(expf(v0-mx)+expf(v1-mx)+expf(v2-mx)+expf(v3-mx));
            if (e == target) nllb = -a;
            b3 = b2; b2 = b1; b1 = b0; b0 = a;
        }
        nll_s[tid] = nllb;
    }
    __syncthreads();
    if (tid == 0){
        float tot = 0.f; int lsum = 0;
        for (int i = 0; i < 32; i++){ tot += nll_s[i]; lsum += lengths[i]; }
        out[0] = tot / (float)(lsum - 64);
    }
}

extern "C" void kernel_launch(void* const* d_in, const int* in_sizes, int n_in,
                              void* d_out, int out_size, void* d_ws, size_t ws_size,
                              hipStream_t stream)
{
    const int*   x        = (const int*)  d_in[0];
    const int*   lengths  = (const int*)  d_in[1];
    const float* emb      = (const float*)d_in[2];
    const float* e2v_b    = (const float*)d_in[3];
    const float* enc_Wih  = (const float*)d_in[4];
    const float* enc_Whh  = (const float*)d_in[5];
    const float* enc_bih  = (const float*)d_in[6];
    const float* enc_bhh  = (const float*)d_in[7];
    const float* enc_h0   = (const float*)d_in[8];
    const float* enc_c0   = (const float*)d_in[9];
    const float* dec_Wih  = (const float*)d_in[10];
    const float* dec_Whh  = (const float*)d_in[11];
    const float* dec_bih  = (const float*)d_in[12];
    const float* dec_bhh  = (const float*)d_in[13];
    const float* dht_W    = (const float*)d_in[14];
    const float* dht_b    = (const float*)d_in[15];
    const float* sos_W    = (const float*)d_in[16];
    const float* sos_b    = (const float*)d_in[17];
    float* out = (float*)d_out;

    char* wsb = (char*)d_ws;
    size_t off = 0;
    auto alloc = [&](size_t elems)->float*{
        float* p = (float*)(wsb + off);
        off += ((elems*sizeof(float) + 255)/256)*256;
        return p;
    };
    float* emb_in  = alloc((size_t)4096*256);
    float* is_s    = alloc(4096);
    float* Xg_enc  = alloc((size_t)4096*1024);   // reused as XgI after encoder
    float* enc_out = alloc((size_t)4096*256);
    float* sos     = alloc((size_t)4032*256);
    float* dec_h   = alloc((size_t)4032*256);
    float* dec_c   = alloc((size_t)4032*256);
    float* gbuf    = alloc((size_t)4032*1024);
    float* dec_out = alloc((size_t)5*4032*256);
    float* bias_e  = alloc(1024);
    float* bias_d  = alloc(1024);
    float* pm      = alloc((size_t)2*20160);
    float* ps      = alloc((size_t)2*20160);
    float* pzt     = alloc((size_t)2*20160);
    float* pze     = alloc((size_t)2*20160);
    float* tlp     = alloc((size_t)4*126*32);
    float* eosb    = alloc((size_t)4*126*32);
    float* seg_g   = alloc((size_t)126*4*32);
    uint32* WhhPK  = (uint32*)alloc((size_t)131072);
    (void)ws_size; (void)in_sizes; (void)n_in; (void)out_size;

    // allow 152064B dynamic LDS for the encoder kernel
    hipFuncSetAttribute(reinterpret_cast<const void*>(k_enc_rnn),
                        hipFuncAttributeMaxDynamicSharedMemorySize, 152064);

    // 0. zero dec_c (d_ws is poisoned 0xAA every call)
    hipMemsetAsync(dec_c, 0, (size_t)4032*256*sizeof(float), stream);
    // 1. bias sums + Whh f16 pack
    k_prep<<<4, 256, 0, stream>>>(enc_bih, enc_bhh, bias_e, dec_bih, dec_bhh, bias_d);
    k_prep_w<<<512, 256, 0, stream>>>(enc_Whh, WhhPK);
    // 2. embeddings + is_single
    k_embed<<<4096, 256, 0, stream>>>(x, emb, emb_in, is_s);
    // 3. encoder input-side gates: Xg_enc = emb_in @ enc_Wih^T + (bih+bhh)
    k_gemm<<<dim3(16,64), 256, 0, stream>>>(emb_in, enc_Wih, bias_e, Xg_enc, 256, 1024, GF_BIAS, nullptr, nullptr, 0);
    // 4. encoder recurrence (32 blocks, weights VGPR+LDS resident / L2-streamed)
    k_enc_rnn<<<32, 1024, 152064, stream>>>(Xg_enc, WhhPK, enc_h0, enc_c0, enc_out);
    // 5. sos = enc_prev @ sos_W^T + sos_b
    k_gemm<<<dim3(4,63), 256, 0, stream>>>(enc_out, sos_W, sos_b, sos, 256, 256, GF_BIAS, nullptr, nullptr, 0);
    // 6. dec_h0 = tanh(enc_prev @ dht_W^T + dht_b)
    k_gemm<<<dim3(4,63), 256, 0, stream>>>(enc_out, dht_W, dht_b, dec_h, 256, 256, GF_BIAS|GF_TANH, nullptr, nullptr, 0);
    // 8. input gates for decoder step 0: gbuf = sos @ dec_Wih^T + (bih+bhh)
    k_gemm<<<dim3(16,63), 256, 0, stream>>>(sos, dec_Wih, bias_d, gbuf, 256, 1024, GF_BIAS, nullptr, nullptr, 0);
    // 9. input gates for steps >=1: XgI = emb_in @ dec_Wih^T + bias (reuses Xg_enc)
    k_gemm<<<dim3(16,64), 256, 0, stream>>>(emb_in, dec_Wih, bias_d, Xg_enc, 256, 1024, GF_BIAS, nullptr, nullptr, 0);
    // 10. decoder recurrence (5 steps)
    for (int j = 0; j < 5; j++){
        if (j == 0){
            k_gemm<<<dim3(16,63), 256, 0, stream>>>(dec_h, dec_Whh, nullptr, gbuf, 256, 1024, GF_ACC, nullptr, nullptr, 0);
        } else {
            k_gemm<<<dim3(16,63), 256, 0, stream>>>(dec_h, dec_Whh, nullptr, gbuf, 256, 1024, GF_DECSTEP, Xg_enc, bias_d, j);
        }
        k_pointwise<<<4032, 256, 0, stream>>>(gbuf, dec_h, dec_c, dec_out + (size_t)j*4032*256);
    }
    // 11. fused logits + logsumexp + tgt/EOS extraction
    k_logits<<<dim3(315,2), 256, 0, stream>>>(dec_out, emb, e2v_b, x, pm, ps, pzt, pze);
    // 12. combine halves
    k_combine<<<79, 256, 0, stream>>>(pm, ps, pzt, pze, tlp, eosb);
    // 13. segmental DP + reduction
    k_finalize<<<1, 128, 0, stream>>>(tlp, eosb, is_s, lengths, seg_g, out);
}

// Round 4
// 1076.269 us; speedup vs baseline: 2.5912x; 1.5487x over previous
//
#include <hip/hip_runtime.h>
#include <math.h>

// SegmentalLM forward. V=4000 E=H=256 M=128 B=32 L=4, S=126, NROW=5*4032=20160.
//
// R3: encoder = 1 block/batch, Whh f16-packed, VGPR+LDS resident (L2 stream 7x cut).
// R4: logits GEMM -> f16 MFMA (16x16x32), fused exp-sum (constant-shift, no online
//     max), tgt/EOS extraction split into k_extract. Old fp32 logits ran 763us at
//     54TF vector; MFMA path targets ~30% of 2382TF f16 ceiling.

#define LOGNEG -1000000.0f
#define GF_BIAS 1
#define GF_TANH 2
#define GF_DECSTEP 4
#define GF_ACC 8
#define ZSHIFT 8.0f

typedef unsigned int uint32;
typedef _Float16 half2_t __attribute__((ext_vector_type(2)));
typedef _Float16 half8_t __attribute__((ext_vector_type(8)));
typedef float    f32x4_t __attribute__((ext_vector_type(4)));

__device__ __forceinline__ float sigmf_(float x){ return 1.0f/(1.0f+expf(-x)); }

__device__ __forceinline__ float dot2f(uint32 w, uint32 h, float acc){
#if __has_builtin(__builtin_amdgcn_fdot2)
    return __builtin_amdgcn_fdot2(__builtin_bit_cast(half2_t, w),
                                  __builtin_bit_cast(half2_t, h), acc, false);
#else
    half2_t a = __builtin_bit_cast(half2_t, w);
    half2_t b = __builtin_bit_cast(half2_t, h);
    return acc + (float)a[0]*(float)b[0] + (float)a[1]*(float)b[1];
#endif
}

// ---------------- embed + is_single ----------------
__global__ __launch_bounds__(256) void k_embed(
    const int* __restrict__ x, const float* __restrict__ emb,
    float* __restrict__ emb_in, float* __restrict__ is_s)
{
    int ri = blockIdx.x;
    int m = ri >> 5, b = ri & 31;
    int tok = x[b*128 + m];
    int h = threadIdx.x;
    emb_in[(size_t)ri*256 + h] = emb[(size_t)tok*256 + h];
    if (h == 0) is_s[ri] = (tok <= 2) ? LOGNEG : 0.0f;
}

// ---------------- bias sums ----------------
__global__ __launch_bounds__(256) void k_prep(
    const float* __restrict__ ebih, const float* __restrict__ ebhh, float* __restrict__ bias_e,
    const float* __restrict__ dbih, const float* __restrict__ dbhh, float* __restrict__ bias_d)
{
    int j = blockIdx.x*256 + threadIdx.x;
    if (j < 1024){ bias_e[j] = ebih[j]+ebhh[j]; bias_d[j] = dbih[j]+dbhh[j]; }
}

// ---------------- pack enc_Whh (1024x256 f32) -> f16 pair-groups ----------------
__global__ __launch_bounds__(256) void k_prep_w(
    const float* __restrict__ W, uint32* __restrict__ Wpk)
{
    int idx = blockIdx.x*256 + threadIdx.x;   // < 131072
    int pg = idx >> 12, rem = idx & 4095;
    int row = rem >> 2, d = rem & 3;
    int k = pg*8 + d*2;
    union { _Float16 h[2]; uint32 u; } cv;
    cv.h[0] = (_Float16)W[row*256 + k];
    cv.h[1] = (_Float16)W[row*256 + k + 1];
    Wpk[idx] = cv.u;
}

// ---------------- pack emb -> f16 (4032 rows, pad rows zero) + shifted bias ----------------
__global__ __launch_bounds__(256) void k_prep_emb(
    const float* __restrict__ emb, const float* __restrict__ e2v_b,
    _Float16* __restrict__ emb16, float* __restrict__ biasOff)
{
    int row = blockIdx.x;        // < 4032
    int c = threadIdx.x;
    emb16[(size_t)row*256 + c] = (row < 4000) ? (_Float16)emb[(size_t)row*256 + c] : (_Float16)0.0f;
    if (c == 0) biasOff[row] = (row < 4000) ? (e2v_b[row] - ZSHIFT) : -200.0f;
}

// ---------------- generic tiled GEMM: C = A(M,K) @ W(N,K)^T ----------------
__global__ __launch_bounds__(256) void k_gemm(
    const float* __restrict__ A, const float* __restrict__ W,
    const float* __restrict__ bias, float* __restrict__ C,
    int K, int N, int flags,
    const float* __restrict__ XgI, const float* __restrict__ bsum, int jstep)
{
    __shared__ float As[16][68];
    __shared__ float Bs[16][68];
    int tid = threadIdx.x;
    int tx = tid & 15, ty = tid >> 4;
    int rowBlk = blockIdx.y * 64, colBlk = blockIdx.x * 64;
    int lr = tid >> 2;
    int lk = (tid & 3) * 4;
    const float* Aload = A + (size_t)(rowBlk + lr)*K + lk;
    const float* Wload = W + (size_t)(colBlk + lr)*K + lk;
    float acc[4][4] = {};
    for (int kt = 0; kt < K; kt += 16){
        float4 av = *(const float4*)(Aload + kt);
        float4 wv = *(const float4*)(Wload + kt);
        As[lk+0][lr] = av.x; As[lk+1][lr] = av.y; As[lk+2][lr] = av.z; As[lk+3][lr] = av.w;
        Bs[lk+0][lr] = wv.x; Bs[lk+1][lr] = wv.y; Bs[lk+2][lr] = wv.z; Bs[lk+3][lr] = wv.w;
        __syncthreads();
        #pragma unroll
        for (int k = 0; k < 16; k++){
            float4 a4 = *(const float4*)&As[k][ty*4];
            float4 b4 = *(const float4*)&Bs[k][tx*4];
            acc[0][0] += a4.x*b4.x; acc[0][1] += a4.x*b4.y; acc[0][2] += a4.x*b4.z; acc[0][3] += a4.x*b4.w;
            acc[1][0] += a4.y*b4.x; acc[1][1] += a4.y*b4.y; acc[1][2] += a4.y*b4.z; acc[1][3] += a4.y*b4.w;
            acc[2][0] += a4.z*b4.x; acc[2][1] += a4.z*b4.y; acc[2][2] += a4.z*b4.z; acc[2][3] += a4.z*b4.w;
            acc[3][0] += a4.w*b4.x; acc[3][1] += a4.w*b4.y; acc[3][2] += a4.w*b4.z; acc[3][3] += a4.w*b4.w;
        }
        __syncthreads();
    }
    #pragma unroll
    for (int i = 0; i < 4; i++){
        int r = rowBlk + ty*4 + i;
        #pragma unroll
        for (int j = 0; j < 4; j++){
            int c = colBlk + tx*4 + j;
            float v = acc[i][j];
            if (flags & GF_ACC)  v += C[(size_t)r*N + c];
            if (flags & GF_BIAS) v += bias[c];
            if (flags & GF_DECSTEP){
                int s = r >> 5, b = r & 31;
                int m = s + jstep;
                v += (m < 128) ? XgI[((size_t)(m*32+b))*1024 + c] : bsum[c];
            }
            if (flags & GF_TANH) v = tanhf(v);
            C[(size_t)r*N + c] = v;
        }
    }
}

// ---------------- encoder LSTM recurrence (R3) ----------------
__global__ __launch_bounds__(1024) void k_enc_rnn(
    const float* __restrict__ Xg, const uint32* __restrict__ Wpk,
    const float* __restrict__ h0, const float* __restrict__ c0,
    float* __restrict__ enc_out)
{
    extern __shared__ char smem[];
    uint32* wlds = (uint32*)smem;                 // [9][1024][4]
    uint32* h_u  = (uint32*)(smem + 147456);      // 128 dwords = 256 f16
    float*  g_s  = (float*)(smem + 147968);       // 1024
    const int b = blockIdx.x, tid = threadIdx.x;
    const uint4* pk4 = (const uint4*)Wpk;         // [32][1024]

    uint4 wreg[14];
    #pragma unroll
    for (int pg = 0; pg < 14; pg++) wreg[pg] = pk4[pg*1024 + tid];
    #pragma unroll
    for (int i = 0; i < 9; i++) ((uint4*)wlds)[i*1024 + tid] = pk4[(14+i)*1024 + tid];

    float c = 0.f;
    if (tid < 256){
        c = c0[tid];
        ((_Float16*)h_u)[tid] = (_Float16)h0[tid];
    }
    __syncthreads();
    const uint4* hu4 = (const uint4*)h_u;
    const uint4* wl4 = (const uint4*)wlds;

    for (int t = 0; t < 128; t++){
        float xg = Xg[((size_t)(t*32+b))*1024 + tid];
        uint4 sv[9];
        #pragma unroll
        for (int i = 0; i < 9; i++) sv[i] = pk4[(23+i)*1024 + tid];

        float acc = xg;
        #pragma unroll
        for (int pg = 0; pg < 14; pg++){
            uint4 hh = hu4[pg];
            acc = dot2f(wreg[pg].x, hh.x, acc);
            acc = dot2f(wreg[pg].y, hh.y, acc);
            acc = dot2f(wreg[pg].z, hh.z, acc);
            acc = dot2f(wreg[pg].w, hh.w, acc);
        }
        #pragma unroll
        for (int i = 0; i < 9; i++){
            uint4 wv = wl4[i*1024 + tid];
            uint4 hh = hu4[14+i];
            acc = dot2f(wv.x, hh.x, acc);
            acc = dot2f(wv.y, hh.y, acc);
            acc = dot2f(wv.z, hh.z, acc);
            acc = dot2f(wv.w, hh.w, acc);
        }
        #pragma unroll
        for (int i = 0; i < 9; i++){
            uint4 hh = hu4[23+i];
            acc = dot2f(sv[i].x, hh.x, acc);
            acc = dot2f(sv[i].y, hh.y, acc);
            acc = dot2f(sv[i].z, hh.z, acc);
            acc = dot2f(sv[i].w, hh.w, acc);
        }
        g_s[tid] = acc;
        __syncthreads();
        if (tid < 256){
            float gi = g_s[tid], gf = g_s[256+tid], gg = g_s[512+tid], go = g_s[768+tid];
            c = sigmf_(gf)*c + sigmf_(gi)*tanhf(gg);
            float hn = sigmf_(go)*tanhf(c);
            enc_out[((size_t)(t*32+b))*256 + tid] = 0.5f*hn;
            ((_Float16*)h_u)[tid] = (_Float16)hn;
        }
        __syncthreads();
    }
}

// ---------------- decoder LSTM pointwise update (writes f16 dec row) ----------------
__global__ __launch_bounds__(256) void k_pointwise(
    const float* __restrict__ gbuf, float* __restrict__ h, float* __restrict__ c,
    _Float16* __restrict__ dec16_j)
{
    int sb = blockIdx.x, u = threadIdx.x;
    const float* g = gbuf + (size_t)sb*1024;
    float gi = g[u], gf = g[256+u], gg = g[512+u], go = g[768+u];
    float cv = c[(size_t)sb*256+u];
    cv = sigmf_(gf)*cv + sigmf_(gi)*tanhf(gg);
    float hv = sigmf_(go)*tanhf(cv);
    c[(size_t)sb*256+u] = cv;
    h[(size_t)sb*256+u] = hv;
    dec16_j[(size_t)sb*256+u] = (_Float16)hv;
}

// ---------------- logits: f16 MFMA GEMM + fused exp-sum ----------------
// 315 blocks x 256 thr (4 waves). Block rows r0=bx*64; wave w owns rows +w*16.
// Sweep 63 vocab tiles of 64 cols; emb tile staged in LDS (row pad +8 halves).
// A frags (8 x half8) VGPR-resident for the whole sweep. s += exp(z - ZSHIFT)
// directly (no online max; |z| bounded ~20, fp32 sum safe). lse = log(s).
__global__ __launch_bounds__(256) void k_logits(
    const _Float16* __restrict__ dec16, const _Float16* __restrict__ emb16,
    const float* __restrict__ biasOff, float* __restrict__ row_lse)
{
    __shared__ _Float16 Bs[64*264];
    int tid = threadIdx.x;
    int wave = tid >> 6, lane = tid & 63;
    int ln = lane & 15, quad = lane >> 4;
    int r0 = blockIdx.x * 64;

    half8_t a[8];
    const half8_t* Ap = (const half8_t*)(dec16 + (size_t)(r0 + wave*16 + ln)*256 + quad*8);
    #pragma unroll
    for (int ks = 0; ks < 8; ks++) a[ks] = Ap[ks*4];   // stride 32 halves

    float s[4] = {0.f,0.f,0.f,0.f};

    for (int vt = 0; vt < 63; vt++){
        int v0 = vt*64;
        __syncthreads();
        #pragma unroll
        for (int i = 0; i < 8; i++){
            int idx = i*256 + tid;          // < 2048
            int row = idx >> 5, c16 = idx & 31;
            *(uint4*)&Bs[row*264 + c16*8] =
                *(const uint4*)(emb16 + (size_t)(v0+row)*256 + c16*8);
        }
        __syncthreads();

        f32x4_t c4[4];
        #pragma unroll
        for (int ct = 0; ct < 4; ct++){ c4[ct][0]=0.f; c4[ct][1]=0.f; c4[ct][2]=0.f; c4[ct][3]=0.f; }

        #pragma unroll
        for (int ct = 0; ct < 4; ct++){
            const _Float16* bp = &Bs[(ct*16+ln)*264 + quad*8];
            #pragma unroll
            for (int ks = 0; ks < 8; ks++){
                half8_t b = *(const half8_t*)(bp + ks*32);
                c4[ct] = __builtin_amdgcn_mfma_f32_16x16x32_f16(a[ks], b, c4[ct], 0, 0, 0);
            }
        }
        #pragma unroll
        for (int ct = 0; ct < 4; ct++){
            float bb = biasOff[v0 + ct*16 + ln];
            #pragma unroll
            for (int reg = 0; reg < 4; reg++)
                s[reg] += __expf(c4[ct][reg] + bb);
        }
    }
    // reduce across the 16 lanes sharing each row (xor within quad)
    #pragma unroll
    for (int reg = 0; reg < 4; reg++){
        float v = s[reg];
        #pragma unroll
        for (int off = 1; off < 16; off <<= 1) v += __shfl_xor(v, off, 64);
        s[reg] = v;
    }
    if (ln == 0){
        #pragma unroll
        for (int reg = 0; reg < 4; reg++)
            row_lse[r0 + wave*16 + quad*4 + reg] = __logf(s[reg]);   // shifted lse
    }
}

// ---------------- extract z[tgt], z[EOS] -> tlp / eosb ----------------
// 5040 blocks x 256 thr; wave handles one row.
__global__ __launch_bounds__(256) void k_extract(
    const _Float16* __restrict__ dec16, const _Float16* __restrict__ emb16,
    const float* __restrict__ biasOff, const int* __restrict__ x,
    const float* __restrict__ row_lse,
    float* __restrict__ tlp, float* __restrict__ eosb)
{
    int tid = threadIdx.x;
    int wave = tid >> 6, lane = tid & 63;
    int r = blockIdx.x*4 + wave;            // < 20160
    int t = r / 4032, sb = r % 4032;
    int s_ = sb >> 5, b = sb & 31;
    int m = s_ + 1 + t;
    int tg = (m < 128) ? x[b*128 + m] : 0;

    const uint32* dp = (const uint32*)(dec16 + (size_t)r*256) + lane*2;
    const uint32* ep = (const uint32*)(emb16 + (size_t)tg*256) + lane*2;
    const uint32* zp = (const uint32*)(emb16 + (size_t)3*256) + lane*2;
    uint32 d0 = dp[0], d1 = dp[1];
    float zt = dot2f(d1, ep[1], dot2f(d0, ep[0], 0.f));
    float ze = dot2f(d1, zp[1], dot2f(d0, zp[0], 0.f));
    #pragma unroll
    for (int off = 1; off < 64; off <<= 1){
        zt += __shfl_xor(zt, off, 64);
        ze += __shfl_xor(ze, off, 64);
    }
    if (lane == 0){
        float lse = row_lse[r];
        zt += biasOff[tg];
        ze += biasOff[3];
        if (t < 4)  tlp[(t*126+s_)*32 + b]      = zt - lse;
        if (t >= 1) eosb[((t-1)*126+s_)*32 + b] = ze - lse;
    }
}

// ---------------- segmental DP + final reduction ----------------
__global__ __launch_bounds__(128) void k_finalize(
    const float* __restrict__ tlp, const float* __restrict__ eosb,
    const float* __restrict__ is_s, const int* __restrict__ lengths,
    float* __restrict__ seg_g, float* __restrict__ out)
{
    int tid = threadIdx.x;
    int k = tid >> 5, b = tid & 31;
    for (int s = 0; s < 126; s++){
        float cum = 0.f;
        for (int kk = 0; kk <= k; kk++) cum += tlp[(kk*126+s)*32 + b];
        if (k >= 1){
            for (int kk = 1; kk <= k; kk++){
                int m = s+1+kk;
                if (m < 128) cum += is_s[m*32+b];
            }
            cum += is_s[(s+1)*32 + b];
        }
        float lp = cum + eosb[(k*126+s)*32 + b];
        int jl = min(4, 126 - s);
        if (k >= jl) lp = LOGNEG;
        seg_g[(s*4+k)*32 + b] = lp;
    }
    __threadfence_block();
    __syncthreads();
    __shared__ float nll_s[32];
    if (tid < 32){
        int target = lengths[tid] - 2;
        float b0 = 0.f, b1 = LOGNEG, b2 = LOGNEG, b3 = LOGNEG;
        float nllb = 0.f;
        for (int e = 1; e <= 126; e++){
            float v0 = b0 + seg_g[((e-1)*4+0)*32 + tid];
            float v1 = b1 + ((e >= 2) ? seg_g[((e-2)*4+1)*32 + tid] : LOGNEG);
            float v2 = b2 + ((e >= 3) ? seg_g[((e-3)*4+2)*32 + tid] : LOGNEG);
            float v3 = b3 + ((e >= 4) ? seg_g[((e-4)*4+3)*32 + tid] : LOGNEG);
            float mx = fmaxf(fmaxf(v0,v1), fmaxf(v2,v3));
            float a = mx + logf(expf(v0-mx)+expf(v1-mx)+expf(v2-mx)+expf(v3-mx));
            if (e == target) nllb = -a;
            b3 = b2; b2 = b1; b1 = b0; b0 = a;
        }
        nll_s[tid] = nllb;
    }
    __syncthreads();
    if (tid == 0){
        float tot = 0.f; int lsum = 0;
        for (int i = 0; i < 32; i++){ tot += nll_s[i]; lsum += lengths[i]; }
        out[0] = tot / (float)(lsum - 64);
    }
}

extern "C" void kernel_launch(void* const* d_in, const int* in_sizes, int n_in,
                              void* d_out, int out_size, void* d_ws, size_t ws_size,
                              hipStream_t stream)
{
    const int*   x        = (const int*)  d_in[0];
    const int*   lengths  = (const int*)  d_in[1];
    const float* emb      = (const float*)d_in[2];
    const float* e2v_b    = (const float*)d_in[3];
    const float* enc_Wih  = (const float*)d_in[4];
    const float* enc_Whh  = (const float*)d_in[5];
    const float* enc_bih  = (const float*)d_in[6];
    const float* enc_bhh  = (const float*)d_in[7];
    const float* enc_h0   = (const float*)d_in[8];
    const float* enc_c0   = (const float*)d_in[9];
    const float* dec_Wih  = (const float*)d_in[10];
    const float* dec_Whh  = (const float*)d_in[11];
    const float* dec_bih  = (const float*)d_in[12];
    const float* dec_bhh  = (const float*)d_in[13];
    const float* dht_W    = (const float*)d_in[14];
    const float* dht_b    = (const float*)d_in[15];
    const float* sos_W    = (const float*)d_in[16];
    const float* sos_b    = (const float*)d_in[17];
    float* out = (float*)d_out;

    char* wsb = (char*)d_ws;
    size_t off = 0;
    auto alloc = [&](size_t bytes)->void*{
        void* p = (void*)(wsb + off);
        off += ((bytes + 255)/256)*256;
        return p;
    };
    float* emb_in  = (float*)alloc((size_t)4096*256*4);
    float* is_s    = (float*)alloc(4096*4);
    float* Xg_enc  = (float*)alloc((size_t)4096*1024*4);   // reused as XgI
    float* enc_out = (float*)alloc((size_t)4096*256*4);
    float* sos     = (float*)alloc((size_t)4032*256*4);
    float* dec_h   = (float*)alloc((size_t)4032*256*4);
    float* dec_c   = (float*)alloc((size_t)4032*256*4);
    float* gbuf    = (float*)alloc((size_t)4032*1024*4);
    _Float16* dec16= (_Float16*)alloc((size_t)5*4032*256*2);
    float* bias_e  = (float*)alloc(1024*4);
    float* bias_d  = (float*)alloc(1024*4);
    _Float16* emb16= (_Float16*)alloc((size_t)4032*256*2);
    float* biasOff = (float*)alloc(4032*4);
    float* row_lse = (float*)alloc((size_t)20160*4);
    float* tlp     = (float*)alloc((size_t)4*126*32*4);
    float* eosb    = (float*)alloc((size_t)4*126*32*4);
    float* seg_g   = (float*)alloc((size_t)126*4*32*4);
    uint32* WhhPK  = (uint32*)alloc((size_t)131072*4);
    (void)ws_size; (void)in_sizes; (void)n_in; (void)out_size;

    hipFuncSetAttribute(reinterpret_cast<const void*>(k_enc_rnn),
                        hipFuncAttributeMaxDynamicSharedMemorySize, 152064);

    // 0. zero dec_c
    hipMemsetAsync(dec_c, 0, (size_t)4032*256*sizeof(float), stream);
    // 1. bias sums + weight/emb f16 packs
    k_prep<<<4, 256, 0, stream>>>(enc_bih, enc_bhh, bias_e, dec_bih, dec_bhh, bias_d);
    k_prep_w<<<512, 256, 0, stream>>>(enc_Whh, WhhPK);
    k_prep_emb<<<4032, 256, 0, stream>>>(emb, e2v_b, emb16, biasOff);
    // 2. embeddings + is_single
    k_embed<<<4096, 256, 0, stream>>>(x, emb, emb_in, is_s);
    // 3. encoder input-side gates
    k_gemm<<<dim3(16,64), 256, 0, stream>>>(emb_in, enc_Wih, bias_e, Xg_enc, 256, 1024, GF_BIAS, nullptr, nullptr, 0);
    // 4. encoder recurrence
    k_enc_rnn<<<32, 1024, 152064, stream>>>(Xg_enc, WhhPK, enc_h0, enc_c0, enc_out);
    // 5/6. sos + dec_h0
    k_gemm<<<dim3(4,63), 256, 0, stream>>>(enc_out, sos_W, sos_b, sos, 256, 256, GF_BIAS, nullptr, nullptr, 0);
    k_gemm<<<dim3(4,63), 256, 0, stream>>>(enc_out, dht_W, dht_b, dec_h, 256, 256, GF_BIAS|GF_TANH, nullptr, nullptr, 0);
    // 8/9. decoder input-side gates
    k_gemm<<<dim3(16,63), 256, 0, stream>>>(sos, dec_Wih, bias_d, gbuf, 256, 1024, GF_BIAS, nullptr, nullptr, 0);
    k_gemm<<<dim3(16,64), 256, 0, stream>>>(emb_in, dec_Wih, bias_d, Xg_enc, 256, 1024, GF_BIAS, nullptr, nullptr, 0);
    // 10. decoder recurrence (5 steps)
    for (int j = 0; j < 5; j++){
        if (j == 0){
            k_gemm<<<dim3(16,63), 256, 0, stream>>>(dec_h, dec_Whh, nullptr, gbuf, 256, 1024, GF_ACC, nullptr, nullptr, 0);
        } else {
            k_gemm<<<dim3(16,63), 256, 0, stream>>>(dec_h, dec_Whh, nullptr, gbuf, 256, 1024, GF_DECSTEP, Xg_enc, bias_d, j);
        }
        k_pointwise<<<4032, 256, 0, stream>>>(gbuf, dec_h, dec_c, dec16 + (size_t)j*4032*256);
    }
    // 11. MFMA logits + fused exp-sum
    k_logits<<<315, 256, 0, stream>>>(dec16, emb16, biasOff, row_lse);
    // 12. tgt/EOS extraction -> tlp/eosb
    k_extract<<<5040, 256, 0, stream>>>(dec16, emb16, biasOff, x, row_lse, tlp, eosb);
    // 13. segmental DP + reduction
    k_finalize<<<1, 128, 0, stream>>>(tlp, eosb, is_s, lengths, seg_g, out);
}

// Round 5
// 892.334 us; speedup vs baseline: 3.1254x; 1.2061x over previous
//
#include <hip/hip_runtime.h>
#include <math.h>

// SegmentalLM forward. V=4000 E=H=256 M=128 B=32 L=4, S=126, NROW=5*4032=20160.
//
// R3: encoder 1 block/batch (no cross-block sync; R2 showed ~10us/step handshake).
// R4: logits -> f16 MFMA + fused exp-sum (constant shift), k_extract split out.
// R5: (a) all dense GEMMs -> f16 MFMA (k_gemm16, fused epilogues). (b) encoder
//     rebuilt: 512 thr, __launch_bounds__(512,2) to pin 256-VGPR cap (R4 showed
//     VGPR_Count=60 -> compiler rematerialized "resident" weights and streamed
//     368KB/step from L2). Now 192 VGPRs weights + 131KB LDS weights, zero
//     per-step L2 weight traffic.

#define LOGNEG -1000000.0f
#define GF_BIAS 1
#define GF_TANH 2
#define GF_DECSTEP 4
#define GF_ACC 8
#define GF_F16OUT 16
#define ZSHIFT 8.0f

typedef unsigned int uint32;
typedef _Float16 half2_t __attribute__((ext_vector_type(2)));
typedef _Float16 half8_t __attribute__((ext_vector_type(8)));
typedef float    f32x4_t __attribute__((ext_vector_type(4)));

__device__ __forceinline__ float sigmf_(float x){ return 1.0f/(1.0f+expf(-x)); }

__device__ __forceinline__ float dot2f(uint32 w, uint32 h, float acc){
#if __has_builtin(__builtin_amdgcn_fdot2)
    return __builtin_amdgcn_fdot2(__builtin_bit_cast(half2_t, w),
                                  __builtin_bit_cast(half2_t, h), acc, false);
#else
    half2_t a = __builtin_bit_cast(half2_t, w);
    half2_t b = __builtin_bit_cast(half2_t, h);
    return acc + (float)a[0]*(float)b[0] + (float)a[1]*(float)b[1];
#endif
}

// ---------------- fused prep: f16 packs + biases ----------------
// blocks 0..4031: emb16+biasOff | 4032..5055: enc_Wih16 | 5056..6079: dec_Wih16
// 6080..7103: dec_Whh16 | 7104..8127: enc_Whh16 | 8128..8383: sos_W16
// 8384..8639: dht_W16 | 8640..8643: bias sums
__global__ __launch_bounds__(256) void k_prep_pack(
    const float* __restrict__ emb, const float* __restrict__ e2v_b,
    const float* __restrict__ eWih, const float* __restrict__ dWih,
    const float* __restrict__ dWhh, const float* __restrict__ eWhh,
    const float* __restrict__ sosW, const float* __restrict__ dhtW,
    const float* __restrict__ ebih, const float* __restrict__ ebhh,
    const float* __restrict__ dbih, const float* __restrict__ dbhh,
    _Float16* __restrict__ emb16, float* __restrict__ biasOff,
    _Float16* __restrict__ eWih16, _Float16* __restrict__ dWih16,
    _Float16* __restrict__ dWhh16, _Float16* __restrict__ eWhh16,
    _Float16* __restrict__ sosW16, _Float16* __restrict__ dhtW16,
    float* __restrict__ bias_e, float* __restrict__ bias_d)
{
    int bx = blockIdx.x, c = threadIdx.x;
    if (bx < 4032){
        int row = bx;
        emb16[(size_t)row*256 + c] = (row < 4000) ? (_Float16)emb[(size_t)row*256 + c] : (_Float16)0.0f;
        if (c == 0) biasOff[row] = (row < 4000) ? (e2v_b[row] - ZSHIFT) : -200.0f;
    } else if (bx < 5056){
        int r = bx - 4032; eWih16[(size_t)r*256 + c] = (_Float16)eWih[(size_t)r*256 + c];
    } else if (bx < 6080){
        int r = bx - 5056; dWih16[(size_t)r*256 + c] = (_Float16)dWih[(size_t)r*256 + c];
    } else if (bx < 7104){
        int r = bx - 6080; dWhh16[(size_t)r*256 + c] = (_Float16)dWhh[(size_t)r*256 + c];
    } else if (bx < 8128){
        int r = bx - 7104; eWhh16[(size_t)r*256 + c] = (_Float16)eWhh[(size_t)r*256 + c];
    } else if (bx < 8384){
        int r = bx - 8128; sosW16[(size_t)r*256 + c] = (_Float16)sosW[(size_t)r*256 + c];
    } else if (bx < 8640){
        int r = bx - 8384; dhtW16[(size_t)r*256 + c] = (_Float16)dhtW[(size_t)r*256 + c];
    } else {
        int j = (bx - 8640)*256 + c;
        if (j < 1024){ bias_e[j] = ebih[j]+ebhh[j]; bias_d[j] = dbih[j]+dbhh[j]; }
    }
}

// ---------------- embed (f16 gather) + is_single ----------------
__global__ __launch_bounds__(256) void k_embed(
    const int* __restrict__ x, const _Float16* __restrict__ emb16,
    _Float16* __restrict__ emb_in16, float* __restrict__ is_s)
{
    int ri = blockIdx.x;
    int m = ri >> 5, b = ri & 31;
    int tok = x[b*128 + m];
    int h = threadIdx.x;
    emb_in16[(size_t)ri*256 + h] = emb16[(size_t)tok*256 + h];
    if (h == 0) is_s[ri] = (tok <= 2) ? LOGNEG : 0.0f;
}

// ---------------- generic f16 MFMA GEMM: C(M,N) = A(M,256) @ W(N,256)^T ----------------
// grid (N/64, M/64), 256 thr (4 waves). Wave w: rows +w*16. B tile in LDS,
// A-frags in regs. Epilogue: ACC, BIAS, DECSTEP (+XgI/bsum), TANH, F16OUT.
__global__ __launch_bounds__(256) void k_gemm16(
    const _Float16* __restrict__ A, const _Float16* __restrict__ W,
    const float* __restrict__ bias, float* __restrict__ C,
    _Float16* __restrict__ C16, int N, int flags,
    const float* __restrict__ XgI, const float* __restrict__ bsum, int jstep)
{
    __shared__ _Float16 Bs[64*264];
    int tid = threadIdx.x;
    int wave = tid >> 6, lane = tid & 63;
    int ln = lane & 15, quad = lane >> 4;
    int rowBlk = blockIdx.y * 64, colBlk = blockIdx.x * 64;

    #pragma unroll
    for (int i = 0; i < 8; i++){
        int idx = i*256 + tid;               // < 2048
        int row = idx >> 5, c16 = idx & 31;
        *(uint4*)&Bs[row*264 + c16*8] =
            *(const uint4*)(W + (size_t)(colBlk+row)*256 + c16*8);
    }
    half8_t a[8];
    const half8_t* Ap = (const half8_t*)(A + (size_t)(rowBlk + wave*16 + ln)*256 + quad*8);
    #pragma unroll
    for (int ks = 0; ks < 8; ks++) a[ks] = Ap[ks*4];
    __syncthreads();

    #pragma unroll
    for (int ct = 0; ct < 4; ct++){
        f32x4_t c4 = {0.f,0.f,0.f,0.f};
        const _Float16* bp = &Bs[(ct*16+ln)*264 + quad*8];
        #pragma unroll
        for (int ks = 0; ks < 8; ks++){
            half8_t b = *(const half8_t*)(bp + ks*32);
            c4 = __builtin_amdgcn_mfma_f32_16x16x32_f16(a[ks], b, c4, 0, 0, 0);
        }
        int c = colBlk + ct*16 + ln;
        #pragma unroll
        for (int reg = 0; reg < 4; reg++){
            int r = rowBlk + wave*16 + quad*4 + reg;
            float v = c4[reg];
            if (flags & GF_ACC)  v += C[(size_t)r*N + c];
            if (flags & GF_BIAS) v += bias[c];
            if (flags & GF_DECSTEP){
                int s = r >> 5, b_ = r & 31;
                int m = s + jstep;
                v += (m < 128) ? XgI[((size_t)(m*32+b_))*1024 + c] : bsum[c];
            }
            if (flags & GF_TANH) v = tanhf(v);
            if (flags & GF_F16OUT) C16[(size_t)r*N + c] = (_Float16)v;
            else                   C  [(size_t)r*N + c] = v;
        }
    }
}

// ---------------- encoder LSTM recurrence (R5: true VGPR residency) ----------------
// 32 blocks x 512 thr, __launch_bounds__(512,2) -> 256 VGPR cap, 1 block/CU.
// Thread t: gate rows r0=t, r1=t+512. Weights k[0,192) in 192 VGPRs,
// k[192,256) in LDS [chunk][row] (lane-contiguous uint4 -> conflict-free).
// Dyn LDS: 131072 (w) + 512 (h f16) + 4096 (g) = 135680 B.
__global__ __launch_bounds__(512, 2) void k_enc_rnn(
    const float* __restrict__ Xg, const _Float16* __restrict__ Whh16,
    const float* __restrict__ h0, const float* __restrict__ c0,
    _Float16* __restrict__ enc_out16)
{
    extern __shared__ char smem[];
    uint4*  wlds = (uint4*)smem;                   // [8][1024]
    uint32* h_u  = (uint32*)(smem + 131072);       // 128 dwords = 256 f16
    float*  g_s  = (float*)(smem + 131584);        // 1024
    const int b = blockIdx.x, tid = threadIdx.x;
    const int r0 = tid, r1 = tid + 512;

    const uint4* p0 = (const uint4*)(Whh16 + (size_t)r0*256);
    const uint4* p1 = (const uint4*)(Whh16 + (size_t)r1*256);
    uint4 w0[24], w1[24];
    #pragma unroll
    for (int i = 0; i < 24; i++){ w0[i] = p0[i]; w1[i] = p1[i]; }
    #pragma unroll
    for (int i = 0; i < 8; i++){
        wlds[i*1024 + r0] = p0[24 + i];
        wlds[i*1024 + r1] = p1[24 + i];
    }
    float c = 0.f;
    if (tid < 256){
        c = c0[tid];
        ((_Float16*)h_u)[tid] = (_Float16)h0[tid];
    }
    __syncthreads();
    const uint4* hu4 = (const uint4*)h_u;          // 32 k-chunks

    float xg0 = Xg[(size_t)b*1024 + r0];
    float xg1 = Xg[(size_t)b*1024 + r1];
    for (int t = 0; t < 128; t++){
        float nxg0 = 0.f, nxg1 = 0.f;
        if (t < 127){
            nxg0 = Xg[((size_t)((t+1)*32+b))*1024 + r0];
            nxg1 = Xg[((size_t)((t+1)*32+b))*1024 + r1];
        }
        float a0 = 0.f, a1 = 0.f;
        #pragma unroll
        for (int i = 0; i < 24; i++){
            uint4 hh = hu4[i];
            a0 = dot2f(w0[i].x, hh.x, a0); a0 = dot2f(w0[i].y, hh.y, a0);
            a0 = dot2f(w0[i].z, hh.z, a0); a0 = dot2f(w0[i].w, hh.w, a0);
            a1 = dot2f(w1[i].x, hh.x, a1); a1 = dot2f(w1[i].y, hh.y, a1);
            a1 = dot2f(w1[i].z, hh.z, a1); a1 = dot2f(w1[i].w, hh.w, a1);
        }
        #pragma unroll
        for (int i = 0; i < 8; i++){
            uint4 hh = hu4[24 + i];
            uint4 v0 = wlds[i*1024 + r0];
            uint4 v1 = wlds[i*1024 + r1];
            a0 = dot2f(v0.x, hh.x, a0); a0 = dot2f(v0.y, hh.y, a0);
            a0 = dot2f(v0.z, hh.z, a0); a0 = dot2f(v0.w, hh.w, a0);
            a1 = dot2f(v1.x, hh.x, a1); a1 = dot2f(v1.y, hh.y, a1);
            a1 = dot2f(v1.z, hh.z, a1); a1 = dot2f(v1.w, hh.w, a1);
        }
        g_s[r0] = a0 + xg0;
        g_s[r1] = a1 + xg1;
        __syncthreads();
        if (tid < 256){
            float gi = g_s[tid], gf = g_s[256+tid], gg = g_s[512+tid], go = g_s[768+tid];
            c = sigmf_(gf)*c + sigmf_(gi)*tanhf(gg);
            float hn = sigmf_(go)*tanhf(c);
            enc_out16[((size_t)(t*32+b))*256 + tid] = (_Float16)(0.5f*hn);
            ((_Float16*)h_u)[tid] = (_Float16)hn;
        }
        __syncthreads();
        xg0 = nxg0; xg1 = nxg1;
    }
}

// ---------------- decoder LSTM pointwise update ----------------
__global__ __launch_bounds__(256) void k_pointwise(
    const float* __restrict__ gbuf, float* __restrict__ c,
    _Float16* __restrict__ dec16_j, int zero_c)
{
    int sb = blockIdx.x, u = threadIdx.x;
    const float* g = gbuf + (size_t)sb*1024;
    float gi = g[u], gf = g[256+u], gg = g[512+u], go = g[768+u];
    float cv = zero_c ? 0.0f : c[(size_t)sb*256+u];
    cv = sigmf_(gf)*cv + sigmf_(gi)*tanhf(gg);
    float hv = sigmf_(go)*tanhf(cv);
    c[(size_t)sb*256+u] = cv;
    dec16_j[(size_t)sb*256+u] = (_Float16)hv;
}

// ---------------- logits: f16 MFMA GEMM + fused exp-sum ----------------
__global__ __launch_bounds__(256) void k_logits(
    const _Float16* __restrict__ dec16, const _Float16* __restrict__ emb16,
    const float* __restrict__ biasOff, float* __restrict__ row_lse)
{
    __shared__ _Float16 Bs[64*264];
    int tid = threadIdx.x;
    int wave = tid >> 6, lane = tid & 63;
    int ln = lane & 15, quad = lane >> 4;
    int r0 = blockIdx.x * 64;

    half8_t a[8];
    const half8_t* Ap = (const half8_t*)(dec16 + (size_t)(r0 + wave*16 + ln)*256 + quad*8);
    #pragma unroll
    for (int ks = 0; ks < 8; ks++) a[ks] = Ap[ks*4];

    float s[4] = {0.f,0.f,0.f,0.f};

    for (int vt = 0; vt < 63; vt++){
        int v0 = vt*64;
        __syncthreads();
        #pragma unroll
        for (int i = 0; i < 8; i++){
            int idx = i*256 + tid;
            int row = idx >> 5, c16 = idx & 31;
            *(uint4*)&Bs[row*264 + c16*8] =
                *(const uint4*)(emb16 + (size_t)(v0+row)*256 + c16*8);
        }
        __syncthreads();

        #pragma unroll
        for (int ct = 0; ct < 4; ct++){
            f32x4_t c4 = {0.f,0.f,0.f,0.f};
            const _Float16* bp = &Bs[(ct*16+ln)*264 + quad*8];
            #pragma unroll
            for (int ks = 0; ks < 8; ks++){
                half8_t b = *(const half8_t*)(bp + ks*32);
                c4 = __builtin_amdgcn_mfma_f32_16x16x32_f16(a[ks], b, c4, 0, 0, 0);
            }
            float bb = biasOff[v0 + ct*16 + ln];
            #pragma unroll
            for (int reg = 0; reg < 4; reg++)
                s[reg] += __expf(c4[reg] + bb);
        }
    }
    #pragma unroll
    for (int reg = 0; reg < 4; reg++){
        float v = s[reg];
        #pragma unroll
        for (int off = 1; off < 16; off <<= 1) v += __shfl_xor(v, off, 64);
        s[reg] = v;
    }
    if (ln == 0){
        #pragma unroll
        for (int reg = 0; reg < 4; reg++)
            row_lse[r0 + wave*16 + quad*4 + reg] = __logf(s[reg]);
    }
}

// ---------------- extract z[tgt], z[EOS] -> tlp / eosb ----------------
__global__ __launch_bounds__(256) void k_extract(
    const _Float16* __restrict__ dec16, const _Float16* __restrict__ emb16,
    const float* __restrict__ biasOff, const int* __restrict__ x,
    const float* __restrict__ row_lse,
    float* __restrict__ tlp, float* __restrict__ eosb)
{
    int tid = threadIdx.x;
    int wave = tid >> 6, lane = tid & 63;
    int r = blockIdx.x*4 + wave;            // < 20160
    int t = r / 4032, sb = r % 4032;
    int s_ = sb >> 5, b = sb & 31;
    int m = s_ + 1 + t;
    int tg = (m < 128) ? x[b*128 + m] : 0;

    const uint32* dp = (const uint32*)(dec16 + (size_t)r*256) + lane*2;
    const uint32* ep = (const uint32*)(emb16 + (size_t)tg*256) + lane*2;
    const uint32* zp = (const uint32*)(emb16 + (size_t)3*256) + lane*2;
    uint32 d0 = dp[0], d1 = dp[1];
    float zt = dot2f(d1, ep[1], dot2f(d0, ep[0], 0.f));
    float ze = dot2f(d1, zp[1], dot2f(d0, zp[0], 0.f));
    #pragma unroll
    for (int off = 1; off < 64; off <<= 1){
        zt += __shfl_xor(zt, off, 64);
        ze += __shfl_xor(ze, off, 64);
    }
    if (lane == 0){
        float lse = row_lse[r];
        zt += biasOff[tg];
        ze += biasOff[3];
        if (t < 4)  tlp[(t*126+s_)*32 + b]      = zt - lse;
        if (t >= 1) eosb[((t-1)*126+s_)*32 + b] = ze - lse;
    }
}

// ---------------- segmental DP + final reduction ----------------
__global__ __launch_bounds__(128) void k_finalize(
    const float* __restrict__ tlp, const float* __restrict__ eosb,
    const float* __restrict__ is_s, const int* __restrict__ lengths,
    float* __restrict__ seg_g, float* __restrict__ out)
{
    int tid = threadIdx.x;
    int k = tid >> 5, b = tid & 31;
    for (int s = 0; s < 126; s++){
        float cum = 0.f;
        for (int kk = 0; kk <= k; kk++) cum += tlp[(kk*126+s)*32 + b];
        if (k >= 1){
            for (int kk = 1; kk <= k; kk++){
                int m = s+1+kk;
                if (m < 128) cum += is_s[m*32+b];
            }
            cum += is_s[(s+1)*32 + b];
        }
        float lp = cum + eosb[(k*126+s)*32 + b];
        int jl = min(4, 126 - s);
        if (k >= jl) lp = LOGNEG;
        seg_g[(s*4+k)*32 + b] = lp;
    }
    __threadfence_block();
    __syncthreads();
    __shared__ float nll_s[32];
    if (tid < 32){
        int target = lengths[tid] - 2;
        float b0 = 0.f, b1 = LOGNEG, b2 = LOGNEG, b3 = LOGNEG;
        float nllb = 0.f;
        for (int e = 1; e <= 126; e++){
            float v0 = b0 + seg_g[((e-1)*4+0)*32 + tid];
            float v1 = b1 + ((e >= 2) ? seg_g[((e-2)*4+1)*32 + tid] : LOGNEG);
            float v2 = b2 + ((e >= 3) ? seg_g[((e-3)*4+2)*32 + tid] : LOGNEG);
            float v3 = b3 + ((e >= 4) ? seg_g[((e-4)*4+3)*32 + tid] : LOGNEG);
            float mx = fmaxf(fmaxf(v0,v1), fmaxf(v2,v3));
            float a = mx + logf(expf(v0-mx)+expf(v1-mx)+expf(v2-mx)+expf(v3-mx));
            if (e == target) nllb = -a;
            b3 = b2; b2 = b1; b1 = b0; b0 = a;
        }
        nll_s[tid] = nllb;
    }
    __syncthreads();
    if (tid == 0){
        float tot = 0.f; int lsum = 0;
        for (int i = 0; i < 32; i++){ tot += nll_s[i]; lsum += lengths[i]; }
        out[0] = tot / (float)(lsum - 64);
    }
}

extern "C" void kernel_launch(void* const* d_in, const int* in_sizes, int n_in,
                              void* d_out, int out_size, void* d_ws, size_t ws_size,
                              hipStream_t stream)
{
    const int*   x        = (const int*)  d_in[0];
    const int*   lengths  = (const int*)  d_in[1];
    const float* emb      = (const float*)d_in[2];
    const float* e2v_b    = (const float*)d_in[3];
    const float* enc_Wih  = (const float*)d_in[4];
    const float* enc_Whh  = (const float*)d_in[5];
    const float* enc_bih  = (const float*)d_in[6];
    const float* enc_bhh  = (const float*)d_in[7];
    const float* enc_h0   = (const float*)d_in[8];
    const float* enc_c0   = (const float*)d_in[9];
    const float* dec_Wih  = (const float*)d_in[10];
    const float* dec_Whh  = (const float*)d_in[11];
    const float* dec_bih  = (const float*)d_in[12];
    const float* dec_bhh  = (const float*)d_in[13];
    const float* dht_W    = (const float*)d_in[14];
    const float* dht_b    = (const float*)d_in[15];
    const float* sos_W    = (const float*)d_in[16];
    const float* sos_b    = (const float*)d_in[17];
    float* out = (float*)d_out;

    char* wsb = (char*)d_ws;
    size_t off = 0;
    auto alloc = [&](size_t bytes)->void*{
        void* p = (void*)(wsb + off);
        off += ((bytes + 255)/256)*256;
        return p;
    };
    _Float16* emb_in16 = (_Float16*)alloc((size_t)4096*256*2);
    float*    is_s     = (float*)alloc(4096*4);
    float*    Xg_enc   = (float*)alloc((size_t)4096*1024*4);   // reused as XgI
    _Float16* enc_out16= (_Float16*)alloc((size_t)4096*256*2);
    _Float16* sos16    = (_Float16*)alloc((size_t)4032*256*2);
    _Float16* dech0_16 = (_Float16*)alloc((size_t)4032*256*2);
    float*    dec_c    = (float*)alloc((size_t)4032*256*4);
    float*    gbuf     = (float*)alloc((size_t)4032*1024*4);
    _Float16* dec16    = (_Float16*)alloc((size_t)5*4032*256*2);
    float*    bias_e   = (float*)alloc(1024*4);
    float*    bias_d   = (float*)alloc(1024*4);
    _Float16* emb16    = (_Float16*)alloc((size_t)4032*256*2);
    float*    biasOff  = (float*)alloc(4032*4);
    float*    row_lse  = (float*)alloc((size_t)20160*4);
    float*    tlp      = (float*)alloc((size_t)4*126*32*4);
    float*    eosb     = (float*)alloc((size_t)4*126*32*4);
    float*    seg_g    = (float*)alloc((size_t)126*4*32*4);
    _Float16* eWih16   = (_Float16*)alloc((size_t)1024*256*2);
    _Float16* dWih16   = (_Float16*)alloc((size_t)1024*256*2);
    _Float16* dWhh16   = (_Float16*)alloc((size_t)1024*256*2);
    _Float16* eWhh16   = (_Float16*)alloc((size_t)1024*256*2);
    _Float16* sosW16   = (_Float16*)alloc((size_t)256*256*2);
    _Float16* dhtW16   = (_Float16*)alloc((size_t)256*256*2);
    (void)ws_size; (void)in_sizes; (void)n_in; (void)out_size;

    hipFuncSetAttribute(reinterpret_cast<const void*>(k_enc_rnn),
                        hipFuncAttributeMaxDynamicSharedMemorySize, 135680);

    // 1. fused prep (f16 packs + bias sums)
    k_prep_pack<<<8644, 256, 0, stream>>>(emb, e2v_b, enc_Wih, dec_Wih, dec_Whh, enc_Whh,
        sos_W, dht_W, enc_bih, enc_bhh, dec_bih, dec_bhh,
        emb16, biasOff, eWih16, dWih16, dWhh16, eWhh16, sosW16, dhtW16, bias_e, bias_d);
    // 2. embeddings + is_single
    k_embed<<<4096, 256, 0, stream>>>(x, emb16, emb_in16, is_s);
    // 3. encoder input-side gates: Xg_enc = emb_in16 @ eWih16^T + bias_e
    k_gemm16<<<dim3(16,64), 256, 0, stream>>>(emb_in16, eWih16, bias_e, Xg_enc, nullptr,
        1024, GF_BIAS, nullptr, nullptr, 0);
    // 4. encoder recurrence (VGPR+LDS-resident weights, zero per-step L2 stream)
    k_enc_rnn<<<32, 512, 135680, stream>>>(Xg_enc, eWhh16, enc_h0, enc_c0, enc_out16);
    // 5/6. sos16 + dec_h0_16
    k_gemm16<<<dim3(4,63), 256, 0, stream>>>(enc_out16, sosW16, sos_b, nullptr, sos16,
        256, GF_BIAS|GF_F16OUT, nullptr, nullptr, 0);
    k_gemm16<<<dim3(4,63), 256, 0, stream>>>(enc_out16, dhtW16, dht_b, nullptr, dech0_16,
        256, GF_BIAS|GF_TANH|GF_F16OUT, nullptr, nullptr, 0);
    // 7. gbuf = sos16 @ dWih16^T + bias_d
    k_gemm16<<<dim3(16,63), 256, 0, stream>>>(sos16, dWih16, bias_d, gbuf, nullptr,
        1024, GF_BIAS, nullptr, nullptr, 0);
    // 8. XgI = emb_in16 @ dWih16^T + bias_d (reuses Xg_enc)
    k_gemm16<<<dim3(16,64), 256, 0, stream>>>(emb_in16, dWih16, bias_d, Xg_enc, nullptr,
        1024, GF_BIAS, nullptr, nullptr, 0);
    // 9. decoder recurrence (5 steps)
    for (int j = 0; j < 5; j++){
        const _Float16* hA = (j == 0) ? dech0_16 : (dec16 + (size_t)(j-1)*4032*256);
        int fl = (j == 0) ? GF_ACC : GF_DECSTEP;
        k_gemm16<<<dim3(16,63), 256, 0, stream>>>(hA, dWhh16, nullptr, gbuf, nullptr,
            1024, fl, Xg_enc, bias_d, j);
        k_pointwise<<<4032, 256, 0, stream>>>(gbuf, dec_c, dec16 + (size_t)j*4032*256, (j==0)?1:0);
    }
    // 10. MFMA logits + fused exp-sum
    k_logits<<<315, 256, 0, stream>>>(dec16, emb16, biasOff, row_lse);
    // 11. tgt/EOS extraction
    k_extract<<<5040, 256, 0, stream>>>(dec16, emb16, biasOff, x, row_lse, tlp, eosb);
    // 12. segmental DP + reduction
    k_finalize<<<1, 128, 0, stream>>>(tlp, eosb, is_s, lengths, seg_g, out);
}

// Round 6
// 873.495 us; speedup vs baseline: 3.1928x; 1.0216x over previous
//
#include <hip/hip_runtime.h>
#include <math.h>

// SegmentalLM forward. V=4000 E=H=256 M=128 B=32 L=4, S=126, NROW=5*4032=20160.
//
// R3: encoder 1 block/batch (no cross-block sync; R2: ~10us/step handshake).
// R4: logits -> f16 MFMA + fused exp-sum (constant shift).
// R5: all dense GEMMs -> f16 MFMA.
// R6: (a) encoder VGPR residency pinned with amdgpu_waves_per_eu(2,2) (R4/R5
//     showed the compiler ignores the launch_bounds floor and rematerializes
//     weight loads -> 384KB/step L2 stream). (b) decoder step fused into one
//     kernel (4 gate tiles + f16 base + pointwise epilogue; kills fp32 gbuf
//     round-trip). (c) logits split over 2 vocab halves for occupancy.

#define LOGNEG -1000000.0f
#define GF_BIAS 1
#define GF_TANH 2
#define GF_F16OUT 16
#define ZSHIFT 8.0f

typedef unsigned int uint32;
typedef _Float16 half2_t __attribute__((ext_vector_type(2)));
typedef _Float16 half8_t __attribute__((ext_vector_type(8)));
typedef float    f32x4_t __attribute__((ext_vector_type(4)));

__device__ __forceinline__ float sigmf_(float x){ return 1.0f/(1.0f+expf(-x)); }

__device__ __forceinline__ float dot2f(uint32 w, uint32 h, float acc){
#if __has_builtin(__builtin_amdgcn_fdot2)
    return __builtin_amdgcn_fdot2(__builtin_bit_cast(half2_t, w),
                                  __builtin_bit_cast(half2_t, h), acc, false);
#else
    half2_t a = __builtin_bit_cast(half2_t, w);
    half2_t b = __builtin_bit_cast(half2_t, h);
    return acc + (float)a[0]*(float)b[0] + (float)a[1]*(float)b[1];
#endif
}

// ---------------- fused prep: f16 packs + biases ----------------
__global__ __launch_bounds__(256) void k_prep_pack(
    const float* __restrict__ emb, const float* __restrict__ e2v_b,
    const float* __restrict__ eWih, const float* __restrict__ dWih,
    const float* __restrict__ dWhh, const float* __restrict__ eWhh,
    const float* __restrict__ sosW, const float* __restrict__ dhtW,
    const float* __restrict__ ebih, const float* __restrict__ ebhh,
    const float* __restrict__ dbih, const float* __restrict__ dbhh,
    _Float16* __restrict__ emb16, float* __restrict__ biasOff,
    _Float16* __restrict__ eWih16, _Float16* __restrict__ dWih16,
    _Float16* __restrict__ dWhh16, _Float16* __restrict__ eWhh16,
    _Float16* __restrict__ sosW16, _Float16* __restrict__ dhtW16,
    float* __restrict__ bias_e, float* __restrict__ bias_d)
{
    int bx = blockIdx.x, c = threadIdx.x;
    if (bx < 4032){
        int row = bx;
        emb16[(size_t)row*256 + c] = (row < 4000) ? (_Float16)emb[(size_t)row*256 + c] : (_Float16)0.0f;
        if (c == 0) biasOff[row] = (row < 4000) ? (e2v_b[row] - ZSHIFT) : -200.0f;
    } else if (bx < 5056){
        int r = bx - 4032; eWih16[(size_t)r*256 + c] = (_Float16)eWih[(size_t)r*256 + c];
    } else if (bx < 6080){
        int r = bx - 5056; dWih16[(size_t)r*256 + c] = (_Float16)dWih[(size_t)r*256 + c];
    } else if (bx < 7104){
        int r = bx - 6080; dWhh16[(size_t)r*256 + c] = (_Float16)dWhh[(size_t)r*256 + c];
    } else if (bx < 8128){
        int r = bx - 7104; eWhh16[(size_t)r*256 + c] = (_Float16)eWhh[(size_t)r*256 + c];
    } else if (bx < 8384){
        int r = bx - 8128; sosW16[(size_t)r*256 + c] = (_Float16)sosW[(size_t)r*256 + c];
    } else if (bx < 8640){
        int r = bx - 8384; dhtW16[(size_t)r*256 + c] = (_Float16)dhtW[(size_t)r*256 + c];
    } else {
        int j = (bx - 8640)*256 + c;
        if (j < 1024){ bias_e[j] = ebih[j]+ebhh[j]; bias_d[j] = dbih[j]+dbhh[j]; }
    }
}

// ---------------- embed (f16 gather) + is_single ----------------
__global__ __launch_bounds__(256) void k_embed(
    const int* __restrict__ x, const _Float16* __restrict__ emb16,
    _Float16* __restrict__ emb_in16, float* __restrict__ is_s)
{
    int ri = blockIdx.x;
    int m = ri >> 5, b = ri & 31;
    int tok = x[b*128 + m];
    int h = threadIdx.x;
    emb_in16[(size_t)ri*256 + h] = emb16[(size_t)tok*256 + h];
    if (h == 0) is_s[ri] = (tok <= 2) ? LOGNEG : 0.0f;
}

// ---------------- generic f16 MFMA GEMM: C(M,N) = A(M,256) @ W(N,256)^T ----------------
__global__ __launch_bounds__(256) void k_gemm16(
    const _Float16* __restrict__ A, const _Float16* __restrict__ W,
    const float* __restrict__ bias, float* __restrict__ C,
    _Float16* __restrict__ C16, int N, int flags)
{
    __shared__ _Float16 Bs[64*264];
    int tid = threadIdx.x;
    int wave = tid >> 6, lane = tid & 63;
    int ln = lane & 15, quad = lane >> 4;
    int rowBlk = blockIdx.y * 64, colBlk = blockIdx.x * 64;

    #pragma unroll
    for (int i = 0; i < 8; i++){
        int idx = i*256 + tid;
        int row = idx >> 5, c16 = idx & 31;
        *(uint4*)&Bs[row*264 + c16*8] =
            *(const uint4*)(W + (size_t)(colBlk+row)*256 + c16*8);
    }
    half8_t a[8];
    const half8_t* Ap = (const half8_t*)(A + (size_t)(rowBlk + wave*16 + ln)*256 + quad*8);
    #pragma unroll
    for (int ks = 0; ks < 8; ks++) a[ks] = Ap[ks*4];
    __syncthreads();

    #pragma unroll
    for (int ct = 0; ct < 4; ct++){
        f32x4_t c4 = {0.f,0.f,0.f,0.f};
        const _Float16* bp = &Bs[(ct*16+ln)*264 + quad*8];
        #pragma unroll
        for (int ks = 0; ks < 8; ks++){
            half8_t b = *(const half8_t*)(bp + ks*32);
            c4 = __builtin_amdgcn_mfma_f32_16x16x32_f16(a[ks], b, c4, 0, 0, 0);
        }
        int c = colBlk + ct*16 + ln;
        #pragma unroll
        for (int reg = 0; reg < 4; reg++){
            int r = rowBlk + wave*16 + quad*4 + reg;
            float v = c4[reg];
            if (flags & GF_BIAS) v += bias[c];
            if (flags & GF_TANH) v = tanhf(v);
            if (flags & GF_F16OUT) C16[(size_t)r*N + c] = (_Float16)v;
            else                   C  [(size_t)r*N + c] = v;
        }
    }
}

// ---------------- encoder LSTM recurrence ----------------
// 32 blocks x 512 thr. amdgpu_waves_per_eu(2,2) pins exactly 2 waves/EU so the
// 256-VGPR budget is real (R4/R5: compiler chose 4 waves/EU and streamed the
// "resident" weights from L2 every step). Thread t: gate rows t, t+512.
// k[0,192) in 192 VGPRs, k[192,256) in 128KB LDS. Zero per-step weight traffic.
__global__ void __attribute__((amdgpu_flat_work_group_size(512,512), amdgpu_waves_per_eu(2,2)))
k_enc_rnn(
    const float* __restrict__ Xg, const _Float16* __restrict__ Whh16,
    const float* __restrict__ h0, const float* __restrict__ c0,
    _Float16* __restrict__ enc_out16)
{
    extern __shared__ char smem[];
    uint4*  wlds = (uint4*)smem;                   // [8][1024]
    uint32* h_u  = (uint32*)(smem + 131072);       // 128 dwords = 256 f16
    float*  g_s  = (float*)(smem + 131584);        // 1024
    const int b = blockIdx.x, tid = threadIdx.x;
    const int r0 = tid, r1 = tid + 512;

    const uint4* p0 = (const uint4*)(Whh16 + (size_t)r0*256);
    const uint4* p1 = (const uint4*)(Whh16 + (size_t)r1*256);
    uint4 w0[24], w1[24];
    #pragma unroll
    for (int i = 0; i < 24; i++){ w0[i] = p0[i]; w1[i] = p1[i]; }
    #pragma unroll
    for (int i = 0; i < 8; i++){
        wlds[i*1024 + r0] = p0[24 + i];
        wlds[i*1024 + r1] = p1[24 + i];
    }
    float c = 0.f;
    if (tid < 256){
        c = c0[tid];
        ((_Float16*)h_u)[tid] = (_Float16)h0[tid];
    }
    __syncthreads();
    const uint4* hu4 = (const uint4*)h_u;

    float xg0 = Xg[(size_t)b*1024 + r0];
    float xg1 = Xg[(size_t)b*1024 + r1];
    for (int t = 0; t < 128; t++){
        float nxg0 = 0.f, nxg1 = 0.f;
        if (t < 127){
            nxg0 = Xg[((size_t)((t+1)*32+b))*1024 + r0];
            nxg1 = Xg[((size_t)((t+1)*32+b))*1024 + r1];
        }
        float a0 = 0.f, a1 = 0.f;
        #pragma unroll
        for (int i = 0; i < 24; i++){
            uint4 hh = hu4[i];
            a0 = dot2f(w0[i].x, hh.x, a0); a0 = dot2f(w0[i].y, hh.y, a0);
            a0 = dot2f(w0[i].z, hh.z, a0); a0 = dot2f(w0[i].w, hh.w, a0);
            a1 = dot2f(w1[i].x, hh.x, a1); a1 = dot2f(w1[i].y, hh.y, a1);
            a1 = dot2f(w1[i].z, hh.z, a1); a1 = dot2f(w1[i].w, hh.w, a1);
        }
        #pragma unroll
        for (int i = 0; i < 8; i++){
            uint4 hh = hu4[24 + i];
            uint4 v0 = wlds[i*1024 + r0];
            uint4 v1 = wlds[i*1024 + r1];
            a0 = dot2f(v0.x, hh.x, a0); a0 = dot2f(v0.y, hh.y, a0);
            a0 = dot2f(v0.z, hh.z, a0); a0 = dot2f(v0.w, hh.w, a0);
            a1 = dot2f(v1.x, hh.x, a1); a1 = dot2f(v1.y, hh.y, a1);
            a1 = dot2f(v1.z, hh.z, a1); a1 = dot2f(v1.w, hh.w, a1);
        }
        g_s[r0] = a0 + xg0;
        g_s[r1] = a1 + xg1;
        __syncthreads();
        if (tid < 256){
            float gi = g_s[tid], gf = g_s[256+tid], gg = g_s[512+tid], go = g_s[768+tid];
            c = sigmf_(gf)*c + sigmf_(gi)*tanhf(gg);
            float hn = sigmf_(go)*tanhf(c);
            enc_out16[((size_t)(t*32+b))*256 + tid] = (_Float16)(0.5f*hn);
            ((_Float16*)h_u)[tid] = (_Float16)hn;
        }
        __syncthreads();
        xg0 = nxg0; xg1 = nxg1;
    }
}

// ---------------- fused decoder step: 4-gate MFMA + base + LSTM pointwise ----------------
// grid (4, 63): u0 = bx*64 (units), r0 = by*64 (rows). 256 thr, 4 waves.
// Gates staged sequentially through one LDS B-tile; accumulators cg[gate][ct].
// base16: gb16 [4032][1024] (jstep==0, row r) or Xg16 [4096][1024] (row m*32+b,
// bias_d fallback for m>=128). Epilogue: LSTM update, writes dec_c + dec16_j.
__global__ __launch_bounds__(256) void k_dec_step(
    const _Float16* __restrict__ hprev, const _Float16* __restrict__ dWhh16,
    const _Float16* __restrict__ base16, const float* __restrict__ bias_d,
    float* __restrict__ dec_c, _Float16* __restrict__ dec16_j, int jstep)
{
    __shared__ _Float16 Bs[64*264];
    int tid = threadIdx.x;
    int wave = tid >> 6, lane = tid & 63;
    int ln = lane & 15, quad = lane >> 4;
    int u0 = blockIdx.x * 64, r0 = blockIdx.y * 64;

    half8_t a[8];
    const half8_t* Ap = (const half8_t*)(hprev + (size_t)(r0 + wave*16 + ln)*256 + quad*8);
    #pragma unroll
    for (int ks = 0; ks < 8; ks++) a[ks] = Ap[ks*4];

    f32x4_t cg[4][4];
    #pragma unroll
    for (int g = 0; g < 4; g++){
        __syncthreads();
        #pragma unroll
        for (int i = 0; i < 8; i++){
            int idx = i*256 + tid;
            int row = idx >> 5, c16 = idx & 31;
            *(uint4*)&Bs[row*264 + c16*8] =
                *(const uint4*)(dWhh16 + (size_t)(g*256 + u0 + row)*256 + c16*8);
        }
        __syncthreads();
        #pragma unroll
        for (int ct = 0; ct < 4; ct++){
            f32x4_t c4 = {0.f,0.f,0.f,0.f};
            const _Float16* bp = &Bs[(ct*16+ln)*264 + quad*8];
            #pragma unroll
            for (int ks = 0; ks < 8; ks++){
                half8_t b = *(const half8_t*)(bp + ks*32);
                c4 = __builtin_amdgcn_mfma_f32_16x16x32_f16(a[ks], b, c4, 0, 0, 0);
            }
            cg[g][ct] = c4;
        }
    }
    #pragma unroll
    for (int ct = 0; ct < 4; ct++){
        int u = u0 + ct*16 + ln;
        #pragma unroll
        for (int reg = 0; reg < 4; reg++){
            int r = r0 + wave*16 + quad*4 + reg;
            float bi, bf, bg, bo;
            if (jstep == 0){
                const _Float16* bp = base16 + (size_t)r*1024 + u;
                bi = (float)bp[0]; bf = (float)bp[256]; bg = (float)bp[512]; bo = (float)bp[768];
            } else {
                int s = r >> 5, b_ = r & 31;
                int m = s + jstep;
                if (m < 128){
                    const _Float16* bp = base16 + (size_t)(m*32+b_)*1024 + u;
                    bi = (float)bp[0]; bf = (float)bp[256]; bg = (float)bp[512]; bo = (float)bp[768];
                } else {
                    bi = bias_d[u]; bf = bias_d[256+u]; bg = bias_d[512+u]; bo = bias_d[768+u];
                }
            }
            float gi = cg[0][ct][reg] + bi;
            float gf = cg[1][ct][reg] + bf;
            float gg = cg[2][ct][reg] + bg;
            float go = cg[3][ct][reg] + bo;
            float cv = (jstep == 0) ? 0.0f : dec_c[(size_t)r*256 + u];
            cv = sigmf_(gf)*cv + sigmf_(gi)*tanhf(gg);
            float hv = sigmf_(go)*tanhf(cv);
            dec_c[(size_t)r*256 + u] = cv;
            dec16_j[(size_t)r*256 + u] = (_Float16)hv;
        }
    }
}

// ---------------- logits: f16 MFMA GEMM + fused exp-sum (2 vocab halves) ----------------
__global__ __launch_bounds__(256) void k_logits(
    const _Float16* __restrict__ dec16, const _Float16* __restrict__ emb16,
    const float* __restrict__ biasOff, float* __restrict__ ps)
{
    __shared__ _Float16 Bs[64*264];
    int tid = threadIdx.x;
    int wave = tid >> 6, lane = tid & 63;
    int ln = lane & 15, quad = lane >> 4;
    int r0 = blockIdx.x * 64;
    int hf = blockIdx.y;
    int vt0 = hf ? 32 : 0, vt1 = hf ? 63 : 32;

    half8_t a[8];
    const half8_t* Ap = (const half8_t*)(dec16 + (size_t)(r0 + wave*16 + ln)*256 + quad*8);
    #pragma unroll
    for (int ks = 0; ks < 8; ks++) a[ks] = Ap[ks*4];

    float s[4] = {0.f,0.f,0.f,0.f};

    for (int vt = vt0; vt < vt1; vt++){
        int v0 = vt*64;
        __syncthreads();
        #pragma unroll
        for (int i = 0; i < 8; i++){
            int idx = i*256 + tid;
            int row = idx >> 5, c16 = idx & 31;
            *(uint4*)&Bs[row*264 + c16*8] =
                *(const uint4*)(emb16 + (size_t)(v0+row)*256 + c16*8);
        }
        __syncthreads();

        #pragma unroll
        for (int ct = 0; ct < 4; ct++){
            f32x4_t c4 = {0.f,0.f,0.f,0.f};
            const _Float16* bp = &Bs[(ct*16+ln)*264 + quad*8];
            #pragma unroll
            for (int ks = 0; ks < 8; ks++){
                half8_t b = *(const half8_t*)(bp + ks*32);
                c4 = __builtin_amdgcn_mfma_f32_16x16x32_f16(a[ks], b, c4, 0, 0, 0);
            }
            float bb = biasOff[v0 + ct*16 + ln];
            #pragma unroll
            for (int reg = 0; reg < 4; reg++)
                s[reg] += __expf(c4[reg] + bb);
        }
    }
    #pragma unroll
    for (int reg = 0; reg < 4; reg++){
        float v = s[reg];
        #pragma unroll
        for (int off = 1; off < 16; off <<= 1) v += __shfl_xor(v, off, 64);
        s[reg] = v;
    }
    if (ln == 0){
        #pragma unroll
        for (int reg = 0; reg < 4; reg++)
            ps[hf*20160 + r0 + wave*16 + quad*4 + reg] = s[reg];
    }
}

// ---------------- extract z[tgt], z[EOS] -> tlp / eosb ----------------
__global__ __launch_bounds__(256) void k_extract(
    const _Float16* __restrict__ dec16, const _Float16* __restrict__ emb16,
    const float* __restrict__ biasOff, const int* __restrict__ x,
    const float* __restrict__ ps,
    float* __restrict__ tlp, float* __restrict__ eosb)
{
    int tid = threadIdx.x;
    int wave = tid >> 6, lane = tid & 63;
    int r = blockIdx.x*4 + wave;            // < 20160
    int t = r / 4032, sb = r % 4032;
    int s_ = sb >> 5, b = sb & 31;
    int m = s_ + 1 + t;
    int tg = (m < 128) ? x[b*128 + m] : 0;

    const uint32* dp = (const uint32*)(dec16 + (size_t)r*256) + lane*2;
    const uint32* ep = (const uint32*)(emb16 + (size_t)tg*256) + lane*2;
    const uint32* zp = (const uint32*)(emb16 + (size_t)3*256) + lane*2;
    uint32 d0 = dp[0], d1 = dp[1];
    float zt = dot2f(d1, ep[1], dot2f(d0, ep[0], 0.f));
    float ze = dot2f(d1, zp[1], dot2f(d0, zp[0], 0.f));
    #pragma unroll
    for (int off = 1; off < 64; off <<= 1){
        zt += __shfl_xor(zt, off, 64);
        ze += __shfl_xor(ze, off, 64);
    }
    if (lane == 0){
        float lse = __logf(ps[r] + ps[20160 + r]);
        zt += biasOff[tg];
        ze += biasOff[3];
        if (t < 4)  tlp[(t*126+s_)*32 + b]      = zt - lse;
        if (t >= 1) eosb[((t-1)*126+s_)*32 + b] = ze - lse;
    }
}

// ---------------- segmental DP + final reduction ----------------
__global__ __launch_bounds__(128) void k_finalize(
    const float* __restrict__ tlp, const float* __restrict__ eosb,
    const float* __restrict__ is_s, const int* __restrict__ lengths,
    float* __restrict__ seg_g, float* __restrict__ out)
{
    int tid = threadIdx.x;
    int k = tid >> 5, b = tid & 31;
    for (int s = 0; s < 126; s++){
        float cum = 0.f;
        for (int kk = 0; kk <= k; kk++) cum += tlp[(kk*126+s)*32 + b];
        if (k >= 1){
            for (int kk = 1; kk <= k; kk++){
                int m = s+1+kk;
                if (m < 128) cum += is_s[m*32+b];
            }
            cum += is_s[(s+1)*32 + b];
        }
        float lp = cum + eosb[(k*126+s)*32 + b];
        int jl = min(4, 126 - s);
        if (k >= jl) lp = LOGNEG;
        seg_g[(s*4+k)*32 + b] = lp;
    }
    __threadfence_block();
    __syncthreads();
    __shared__ float nll_s[32];
    if (tid < 32){
        int target = lengths[tid] - 2;
        float b0 = 0.f, b1 = LOGNEG, b2 = LOGNEG, b3 = LOGNEG;
        float nllb = 0.f;
        for (int e = 1; e <= 126; e++){
            float v0 = b0 + seg_g[((e-1)*4+0)*32 + tid];
            float v1 = b1 + ((e >= 2) ? seg_g[((e-2)*4+1)*32 + tid] : LOGNEG);
            float v2 = b2 + ((e >= 3) ? seg_g[((e-3)*4+2)*32 + tid] : LOGNEG);
            float v3 = b3 + ((e >= 4) ? seg_g[((e-4)*4+3)*32 + tid] : LOGNEG);
            float mx = fmaxf(fmaxf(v0,v1), fmaxf(v2,v3));
            float a = mx + logf(expf(v0-mx)+expf(v1-mx)+expf(v2-mx)+expf(v3-mx));
            if (e == target) nllb = -a;
            b3 = b2; b2 = b1; b1 = b0; b0 = a;
        }
        nll_s[tid] = nllb;
    }
    __syncthreads();
    if (tid == 0){
        float tot = 0.f; int lsum = 0;
        for (int i = 0; i < 32; i++){ tot += nll_s[i]; lsum += lengths[i]; }
        out[0] = tot / (float)(lsum - 64);
    }
}

extern "C" void kernel_launch(void* const* d_in, const int* in_sizes, int n_in,
                              void* d_out, int out_size, void* d_ws, size_t ws_size,
                              hipStream_t stream)
{
    const int*   x        = (const int*)  d_in[0];
    const int*   lengths  = (const int*)  d_in[1];
    const float* emb      = (const float*)d_in[2];
    const float* e2v_b    = (const float*)d_in[3];
    const float* enc_Wih  = (const float*)d_in[4];
    const float* enc_Whh  = (const float*)d_in[5];
    const float* enc_bih  = (const float*)d_in[6];
    const float* enc_bhh  = (const float*)d_in[7];
    const float* enc_h0   = (const float*)d_in[8];
    const float* enc_c0   = (const float*)d_in[9];
    const float* dec_Wih  = (const float*)d_in[10];
    const float* dec_Whh  = (const float*)d_in[11];
    const float* dec_bih  = (const float*)d_in[12];
    const float* dec_bhh  = (const float*)d_in[13];
    const float* dht_W    = (const float*)d_in[14];
    const float* dht_b    = (const float*)d_in[15];
    const float* sos_W    = (const float*)d_in[16];
    const float* sos_b    = (const float*)d_in[17];
    float* out = (float*)d_out;

    char* wsb = (char*)d_ws;
    size_t off = 0;
    auto alloc = [&](size_t bytes)->void*{
        void* p = (void*)(wsb + off);
        off += ((bytes + 255)/256)*256;
        return p;
    };
    _Float16* emb_in16 = (_Float16*)alloc((size_t)4096*256*2);
    float*    is_s     = (float*)alloc(4096*4);
    float*    Xg_enc   = (float*)alloc((size_t)4096*1024*4);
    _Float16* Xg16     = (_Float16*)alloc((size_t)4096*1024*2);
    _Float16* gb16     = (_Float16*)alloc((size_t)4032*1024*2);
    _Float16* enc_out16= (_Float16*)alloc((size_t)4096*256*2);
    _Float16* sos16    = (_Float16*)alloc((size_t)4032*256*2);
    _Float16* dech0_16 = (_Float16*)alloc((size_t)4032*256*2);
    float*    dec_c    = (float*)alloc((size_t)4032*256*4);
    _Float16* dec16    = (_Float16*)alloc((size_t)5*4032*256*2);
    float*    bias_e   = (float*)alloc(1024*4);
    float*    bias_d   = (float*)alloc(1024*4);
    _Float16* emb16    = (_Float16*)alloc((size_t)4032*256*2);
    float*    biasOff  = (float*)alloc(4032*4);
    float*    ps       = (float*)alloc((size_t)2*20160*4);
    float*    tlp      = (float*)alloc((size_t)4*126*32*4);
    float*    eosb     = (float*)alloc((size_t)4*126*32*4);
    float*    seg_g    = (float*)alloc((size_t)126*4*32*4);
    _Float16* eWih16   = (_Float16*)alloc((size_t)1024*256*2);
    _Float16* dWih16   = (_Float16*)alloc((size_t)1024*256*2);
    _Float16* dWhh16   = (_Float16*)alloc((size_t)1024*256*2);
    _Float16* eWhh16   = (_Float16*)alloc((size_t)1024*256*2);
    _Float16* sosW16   = (_Float16*)alloc((size_t)256*256*2);
    _Float16* dhtW16   = (_Float16*)alloc((size_t)256*256*2);
    (void)ws_size; (void)in_sizes; (void)n_in; (void)out_size;

    hipFuncSetAttribute(reinterpret_cast<const void*>(k_enc_rnn),
                        hipFuncAttributeMaxDynamicSharedMemorySize, 135680);

    // 1. fused prep (f16 packs + bias sums)
    k_prep_pack<<<8644, 256, 0, stream>>>(emb, e2v_b, enc_Wih, dec_Wih, dec_Whh, enc_Whh,
        sos_W, dht_W, enc_bih, enc_bhh, dec_bih, dec_bhh,
        emb16, biasOff, eWih16, dWih16, dWhh16, eWhh16, sosW16, dhtW16, bias_e, bias_d);
    // 2. embeddings + is_single
    k_embed<<<4096, 256, 0, stream>>>(x, emb16, emb_in16, is_s);
    // 3. encoder input-side gates: Xg_enc = emb_in16 @ eWih16^T + bias_e (fp32 out)
    k_gemm16<<<dim3(16,64), 256, 0, stream>>>(emb_in16, eWih16, bias_e, Xg_enc, nullptr,
        1024, GF_BIAS);
    // 4. encoder recurrence (register/LDS-resident weights, pinned occupancy)
    k_enc_rnn<<<32, 512, 135680, stream>>>(Xg_enc, eWhh16, enc_h0, enc_c0, enc_out16);
    // 5/6. sos16 + dec_h0_16
    k_gemm16<<<dim3(4,63), 256, 0, stream>>>(enc_out16, sosW16, sos_b, nullptr, sos16,
        256, GF_BIAS|GF_F16OUT);
    k_gemm16<<<dim3(4,63), 256, 0, stream>>>(enc_out16, dhtW16, dht_b, nullptr, dech0_16,
        256, GF_BIAS|GF_TANH|GF_F16OUT);
    // 7. gb16 = sos16 @ dWih16^T + bias_d (f16)
    k_gemm16<<<dim3(16,63), 256, 0, stream>>>(sos16, dWih16, bias_d, nullptr, gb16,
        1024, GF_BIAS|GF_F16OUT);
    // 8. Xg16 = emb_in16 @ dWih16^T + bias_d (f16)
    k_gemm16<<<dim3(16,64), 256, 0, stream>>>(emb_in16, dWih16, bias_d, nullptr, Xg16,
        1024, GF_BIAS|GF_F16OUT);
    // 9. decoder recurrence: 5 fused steps
    for (int j = 0; j < 5; j++){
        const _Float16* hA = (j == 0) ? dech0_16 : (dec16 + (size_t)(j-1)*4032*256);
        const _Float16* base = (j == 0) ? gb16 : Xg16;
        k_dec_step<<<dim3(4,63), 256, 0, stream>>>(hA, dWhh16, base, bias_d,
            dec_c, dec16 + (size_t)j*4032*256, j);
    }
    // 10. MFMA logits + fused exp-sum (2 vocab halves)
    k_logits<<<dim3(315,2), 256, 0, stream>>>(dec16, emb16, biasOff, ps);
    // 11. tgt/EOS extraction (combines halves)
    k_extract<<<5040, 256, 0, stream>>>(dec16, emb16, biasOff, x, ps, tlp, eosb);
    // 12. segmental DP + reduction
    k_finalize<<<1, 128, 0, stream>>>(tlp, eosb, is_s, lengths, seg_g, out);
}